// Round 1
// baseline (3492.852 us; speedup 1.0000x reference)
//
#include <hip/hip_runtime.h>
#include <hip/hip_bf16.h>

#define NN 50000
#define EE 250000
#define HH 128
#define EPS_ 1e-5f
#define TILE_E 32
#define TPB 4

// ---------------- degree kernels ----------------
__global__ void k_count_deg(const int* __restrict__ bei, const int* __restrict__ cei,
                            float* __restrict__ degb, float* __restrict__ degc) {
  int i = blockIdx.x * blockDim.x + threadIdx.x;
  if (i < EE) {
    atomicAdd(&degb[bei[EE + i]], 1.0f);
  } else if (i < 2 * EE) {
    atomicAdd(&degc[cei[EE + (i - EE)]], 1.0f);
  }
}

__global__ void k_finalize_deg(float* __restrict__ deg) {  // 2N entries -> dinv
  int i = blockIdx.x * blockDim.x + threadIdx.x;
  if (i < 2 * NN) deg[i] = rsqrtf(deg[i] + 1.0f);
}

// ---------------- encoder: relu(x@W_enc+b), accumulate BN stats ----------------
__global__ void k_encoder(const float* __restrict__ x, const float* __restrict__ W,
                          const float* __restrict__ b, float* __restrict__ A,
                          float* __restrict__ sum, float* __restrict__ sumsq) {
  int t = threadIdx.x;
  int c = t & 127, r = t >> 7;  // r in {0,1}
  int n0 = blockIdx.x * 64;
  float w0 = W[c], w1 = W[HH + c], w2 = W[2 * HH + c], bb = b[c];
  float ls = 0.f, lss = 0.f;
  for (int rr = r; rr < 64; rr += 2) {
    int n = n0 + rr;
    if (n < NN) {
      float v = fmaxf(x[n * 3] * w0 + x[n * 3 + 1] * w1 + x[n * 3 + 2] * w2 + bb, 0.f);
      A[(size_t)n * HH + c] = v;
      ls += v; lss += v * v;
    }
  }
  __shared__ float red[2][HH];
  red[r][c] = ls; __syncthreads();
  if (r == 0) atomicAdd(&sum[c], red[0][c] + red[1][c]);
  __syncthreads();
  red[r][c] = lss; __syncthreads();
  if (r == 0) atomicAdd(&sumsq[c], red[0][c] + red[1][c]);
}

// ---------------- BN finalize: scale/shift from sums ----------------
__global__ void k_bn_finalize(const float* __restrict__ sum, const float* __restrict__ sumsq,
                              const float* __restrict__ g, const float* __restrict__ be,
                              float* __restrict__ scale, float* __restrict__ shift, float invn) {
  int c = threadIdx.x;
  float m = sum[c] * invn;
  float v = fmaxf(sumsq[c] * invn - m * m, 0.f);
  float s = g[c] * rsqrtf(v + EPS_);
  scale[c] = s;
  shift[c] = be[c] - m * s;
}

__global__ void k_bn_apply(float* __restrict__ A, const float* __restrict__ scale,
                           const float* __restrict__ shift) {
  int i = blockIdx.x * 256 + threadIdx.x;
  if (i < NN * HH) {
    int c = i & 127;
    A[i] = A[i] * scale[c] + shift[c];
  }
}

// ---------------- GEMM: Y[N,H] = (relu?)(X) @ W[H,H] ----------------
template <int RELU>
__global__ void k_gemm_nh(const float* __restrict__ X, const float* __restrict__ W,
                          float* __restrict__ Y) {
  __shared__ float As[64][32];
  __shared__ float Ws[32][HH];
  int t = threadIdx.x;
  int tx = t & 31, ty = t >> 5;  // col = tx*4 .. +3 ; rows = ty*8 .. +7
  int row0 = blockIdx.x * 64;
  float acc[8][4];
#pragma unroll
  for (int i = 0; i < 8; ++i)
#pragma unroll
    for (int q = 0; q < 4; ++q) acc[i][q] = 0.f;

  for (int kc = 0; kc < HH; kc += 32) {
#pragma unroll
    for (int it = 0; it < 8; ++it) {  // stage A: 64x32
      int idx = t + it * 256;
      int rr = idx >> 5, kk = idx & 31;
      int row = row0 + rr;
      float v = (row < NN) ? X[(size_t)row * HH + kc + kk] : 0.f;
      if (RELU) v = fmaxf(v, 0.f);
      As[rr][kk] = v;
    }
#pragma unroll
    for (int it = 0; it < 16; ++it) {  // stage W: 32x128
      int idx = t + it * 256;
      int kk = idx >> 7, cc = idx & 127;
      Ws[kk][cc] = W[(size_t)(kc + kk) * HH + cc];
    }
    __syncthreads();
#pragma unroll
    for (int k = 0; k < 32; ++k) {
      float4 bv = *reinterpret_cast<float4*>(&Ws[k][tx * 4]);
#pragma unroll
      for (int i = 0; i < 8; ++i) {
        float a = As[ty * 8 + i][k];
        acc[i][0] += a * bv.x; acc[i][1] += a * bv.y;
        acc[i][2] += a * bv.z; acc[i][3] += a * bv.w;
      }
    }
    __syncthreads();
  }
#pragma unroll
  for (int i = 0; i < 8; ++i) {
    int row = row0 + ty * 8 + i;
    if (row < NN) {
      float4 v = make_float4(acc[i][0], acc[i][1], acc[i][2], acc[i][3]);
      *reinterpret_cast<float4*>(&Y[(size_t)row * HH + tx * 4]) = v;
    }
  }
}

// ---------------- GCN self-loop + bias: OUT (=|+=) bias + dinv^2 * C ----------------
__global__ void k_gcn_self(const float* __restrict__ C, const float* __restrict__ dinv,
                           const float* __restrict__ bias, float* __restrict__ OUT, int add) {
  int i = blockIdx.x * 256 + threadIdx.x;
  if (i >= NN * HH) return;
  int n = i >> 7, c = i & 127;
  float d = dinv[n];
  float v = bias[c] + d * d * C[i];
  if (add) OUT[i] += v; else OUT[i] = v;
}

// ---------------- GCN edge scatter: OUT[dst] += dinv[s]*dinv[d]*C[src] ----------------
__global__ void k_scatter(const float* __restrict__ C, const int* __restrict__ ei,
                          const float* __restrict__ dinv, float* __restrict__ OUT) {
  int t = threadIdx.x;
  int e = blockIdx.x * 2 + (t >> 7);
  int c = t & 127;
  if (e >= EE) return;
  int s = ei[e], d = ei[EE + e];
  float w = dinv[s] * dinv[d];
  atomicAdd(&OUT[(size_t)d * HH + c], w * C[(size_t)s * HH + c]);
}

// ---------------- edge MLP: t = relu(concat(h2[s],h2[d]) @ W1 + b1) ----------------
// PASS2=0: accumulate BN stats of t.   PASS2=1: recompute t, apply BN, out = t_hat@W2 + b2.
template <int PASS2>
__global__ void k_edge_mlp(const float* __restrict__ h2, const int* __restrict__ ei,
                           const float* __restrict__ W1, const float* __restrict__ b1,
                           float* __restrict__ sum, float* __restrict__ sumsq,
                           const float* __restrict__ scale, const float* __restrict__ shift,
                           const float* __restrict__ W2, const float* __restrict__ b2,
                           float* __restrict__ out) {
  __shared__ float Us[TILE_E][64];
  __shared__ float Wc[64][HH];
  __shared__ int Se[TILE_E], De[TILE_E];
  __shared__ float red[8][HH];
  __shared__ float red2[TILE_E][2];
  __shared__ float Ws2[HH * 2];
  int t = threadIdx.x;
  int tx = t & 31, ty = t >> 5;
  float ls[4] = {0, 0, 0, 0}, lss[4] = {0, 0, 0, 0};
  if (PASS2) Ws2[t] = W2[t];  // 256 threads = H*2 elements

  for (int tile = 0; tile < TPB; ++tile) {
    int e0 = (blockIdx.x * TPB + tile) * TILE_E;
    if (e0 >= EE) break;
    if (t < TILE_E) {
      int eg = e0 + t;
      Se[t] = (eg < EE) ? ei[eg] : 0;
      De[t] = (eg < EE) ? ei[EE + eg] : 0;
    }
    __syncthreads();
    float acc[4][4];
#pragma unroll
    for (int i = 0; i < 4; ++i)
#pragma unroll
      for (int q = 0; q < 4; ++q) acc[i][q] = 0.f;

    for (int kc = 0; kc < 2 * HH; kc += 64) {
#pragma unroll
      for (int it = 0; it < 8; ++it) {  // stage U chunk: 32x64 gathered
        int idx = t + it * 256;
        int e = idx >> 6, k = idx & 63;
        int gk = kc + k;
        int row = (gk < HH) ? Se[e] : De[e];
        Us[e][k] = h2[(size_t)row * HH + (gk & 127)];
      }
#pragma unroll
      for (int it = 0; it < 32; ++it) {  // stage W chunk: 64x128
        int idx = t + it * 256;
        int kk = idx >> 7, cc = idx & 127;
        Wc[kk][cc] = W1[(size_t)(kc + kk) * HH + cc];
      }
      __syncthreads();
#pragma unroll
      for (int k = 0; k < 64; ++k) {
        float4 bv = *reinterpret_cast<float4*>(&Wc[k][tx * 4]);
#pragma unroll
        for (int i = 0; i < 4; ++i) {
          float a = Us[ty * 4 + i][k];
          acc[i][0] += a * bv.x; acc[i][1] += a * bv.y;
          acc[i][2] += a * bv.z; acc[i][3] += a * bv.w;
        }
      }
      __syncthreads();
    }

    if (!PASS2) {
#pragma unroll
      for (int i = 0; i < 4; ++i) {
        int eg = e0 + ty * 4 + i;
        if (eg < EE) {
#pragma unroll
          for (int q = 0; q < 4; ++q) {
            float v = fmaxf(acc[i][q] + b1[tx * 4 + q], 0.f);
            ls[q] += v; lss[q] += v * v;
          }
        }
      }
    } else {
      if (t < TILE_E * 2) red2[t >> 1][t & 1] = 0.f;
      __syncthreads();
#pragma unroll
      for (int i = 0; i < 4; ++i) {
        float p0 = 0.f, p1 = 0.f;
#pragma unroll
        for (int q = 0; q < 4; ++q) {
          int c = tx * 4 + q;
          float v = fmaxf(acc[i][q] + b1[c], 0.f);
          v = v * scale[c] + shift[c];
          p0 += v * Ws2[c * 2];
          p1 += v * Ws2[c * 2 + 1];
        }
        atomicAdd(&red2[ty * 4 + i][0], p0);
        atomicAdd(&red2[ty * 4 + i][1], p1);
      }
      __syncthreads();
      if (t < TILE_E * 2) {
        int el = t >> 1, j = t & 1;
        int eg = e0 + el;
        if (eg < EE) out[(size_t)eg * 2 + j] = red2[el][j] + b2[j];
      }
      __syncthreads();
    }
  }

  if (!PASS2) {
#pragma unroll
    for (int q = 0; q < 4; ++q) red[ty][tx * 4 + q] = ls[q];
    __syncthreads();
    if (t < HH) {
      float s = 0.f;
#pragma unroll
      for (int y = 0; y < 8; ++y) s += red[y][t];
      atomicAdd(&sum[t], s);
    }
    __syncthreads();
#pragma unroll
    for (int q = 0; q < 4; ++q) red[ty][tx * 4 + q] = lss[q];
    __syncthreads();
    if (t < HH) {
      float s = 0.f;
#pragma unroll
      for (int y = 0; y < 8; ++y) s += red[y][t];
      atomicAdd(&sumsq[t], s);
    }
  }
}

// ---------------- edge types: zeros(E) then ones(E), as float ----------------
__global__ void k_edge_types(float* __restrict__ out) {
  int i = blockIdx.x * 256 + threadIdx.x;
  if (i < 2 * EE) out[(size_t)2 * EE * 2 + i] = (i < EE) ? 0.0f : 1.0f;
}

extern "C" void kernel_launch(void* const* d_in, const int* in_sizes, int n_in,
                              void* d_out, int out_size, void* d_ws, size_t ws_size,
                              hipStream_t stream) {
  const float* x      = (const float*)d_in[0];
  const int*   bei    = (const int*)d_in[1];
  const int*   cei    = (const int*)d_in[2];
  const float* W_enc  = (const float*)d_in[3];
  const float* b_enc  = (const float*)d_in[4];
  const float* g_enc  = (const float*)d_in[5];
  const float* be_enc = (const float*)d_in[6];
  const float* W1b = (const float*)d_in[7];  const float* b1b = (const float*)d_in[8];
  const float* W1c = (const float*)d_in[9];  const float* b1c = (const float*)d_in[10];
  const float* W2b = (const float*)d_in[11]; const float* b2b = (const float*)d_in[12];
  const float* W2c = (const float*)d_in[13]; const float* b2c = (const float*)d_in[14];
  const float* Wbp1 = (const float*)d_in[15]; const float* bbp1 = (const float*)d_in[16];
  const float* gbp  = (const float*)d_in[17]; const float* bebp = (const float*)d_in[18];
  const float* Wbp2 = (const float*)d_in[19]; const float* bbp2 = (const float*)d_in[20];
  const float* Wcp1 = (const float*)d_in[21]; const float* bcp1 = (const float*)d_in[22];
  const float* gcp  = (const float*)d_in[23]; const float* becp = (const float*)d_in[24];
  const float* Wcp2 = (const float*)d_in[25]; const float* bcp2 = (const float*)d_in[26];
  float* out = (float*)d_out;

  float* ws = (float*)d_ws;
  float* A = ws;                         // h, later h2   [N*H]
  float* B = A + (size_t)NN * HH;        // h1            [N*H]
  float* C = B + (size_t)NN * HH;        // xw tmp        [N*H]
  float* degb = C + (size_t)NN * HH;     // dinv beam     [N]
  float* degc = degb + NN;               // dinv col      [N]
  float* st   = degc + NN;               // sum,sumsq,scale,shift [4*H]
  float* s_sum = st, *s_sq = st + HH, *s_scale = st + 2 * HH, *s_shift = st + 3 * HH;

  hipMemsetAsync(degb, 0, sizeof(float) * 2 * NN, stream);
  hipMemsetAsync(st, 0, sizeof(float) * 2 * HH, stream);
  k_count_deg<<<(2 * EE + 255) / 256, 256, 0, stream>>>(bei, cei, degb, degc);
  k_finalize_deg<<<(2 * NN + 255) / 256, 256, 0, stream>>>(degb);

  // encoder + BN
  k_encoder<<<(NN + 63) / 64, 256, 0, stream>>>(x, W_enc, b_enc, A, s_sum, s_sq);
  k_bn_finalize<<<1, 128, 0, stream>>>(s_sum, s_sq, g_enc, be_enc, s_scale, s_shift, 1.0f / NN);
  k_bn_apply<<<(NN * HH + 255) / 256, 256, 0, stream>>>(A, s_scale, s_shift);

  int gblk = (NN + 63) / 64;
  int eblk = (NN * HH + 255) / 256;
  int sblk = (EE + 1) / 2;
  // GCN layer 1: h1 = relu(gcn_b(h) + gcn_c(h)) ; relu applied on read in layer 2
  k_gemm_nh<0><<<gblk, 256, 0, stream>>>(A, W1b, C);
  k_gcn_self<<<eblk, 256, 0, stream>>>(C, degb, b1b, B, 0);
  k_scatter<<<sblk, 256, 0, stream>>>(C, bei, degb, B);
  k_gemm_nh<0><<<gblk, 256, 0, stream>>>(A, W1c, C);
  k_gcn_self<<<eblk, 256, 0, stream>>>(C, degc, b1c, B, 1);
  k_scatter<<<sblk, 256, 0, stream>>>(C, cei, degc, B);
  // GCN layer 2: h2 = gcn_b(relu(h1)) + gcn_c(relu(h1))  -> into A
  k_gemm_nh<1><<<gblk, 256, 0, stream>>>(B, W2b, C);
  k_gcn_self<<<eblk, 256, 0, stream>>>(C, degb, b2b, A, 0);
  k_scatter<<<sblk, 256, 0, stream>>>(C, bei, degb, A);
  k_gemm_nh<1><<<gblk, 256, 0, stream>>>(B, W2c, C);
  k_gcn_self<<<eblk, 256, 0, stream>>>(C, degc, b2c, A, 1);
  k_scatter<<<sblk, 256, 0, stream>>>(C, cei, degc, A);

  // edge predictors
  int mblk = (EE + TPB * TILE_E - 1) / (TPB * TILE_E);
  hipMemsetAsync(st, 0, sizeof(float) * 2 * HH, stream);
  k_edge_mlp<0><<<mblk, 256, 0, stream>>>(A, bei, Wbp1, bbp1, s_sum, s_sq,
                                          nullptr, nullptr, nullptr, nullptr, nullptr);
  k_bn_finalize<<<1, 128, 0, stream>>>(s_sum, s_sq, gbp, bebp, s_scale, s_shift, 1.0f / EE);
  k_edge_mlp<1><<<mblk, 256, 0, stream>>>(A, bei, Wbp1, bbp1, nullptr, nullptr,
                                          s_scale, s_shift, Wbp2, bbp2, out);
  hipMemsetAsync(st, 0, sizeof(float) * 2 * HH, stream);
  k_edge_mlp<0><<<mblk, 256, 0, stream>>>(A, cei, Wcp1, bcp1, s_sum, s_sq,
                                          nullptr, nullptr, nullptr, nullptr, nullptr);
  k_bn_finalize<<<1, 128, 0, stream>>>(s_sum, s_sq, gcp, becp, s_scale, s_shift, 1.0f / EE);
  k_edge_mlp<1><<<mblk, 256, 0, stream>>>(A, cei, Wcp1, bcp1, nullptr, nullptr,
                                          s_scale, s_shift, Wcp2, bcp2, out + (size_t)2 * EE);

  k_edge_types<<<(2 * EE + 255) / 256, 256, 0, stream>>>(out);
}

// Round 2
// 1229.113 us; speedup vs baseline: 2.8418x; 2.8418x over previous
//
#include <hip/hip_runtime.h>
#include <hip/hip_bf16.h>

#define NN 50000
#define EE 250000
#define HH 128
#define EPS_ 1e-5f

typedef __attribute__((ext_vector_type(8))) short bf16x8;
typedef __attribute__((ext_vector_type(4))) float f32x4;

// ---------------- degree kernels ----------------
__global__ void k_count_deg(const int* __restrict__ bei, const int* __restrict__ cei,
                            float* __restrict__ degb, float* __restrict__ degc) {
  int i = blockIdx.x * blockDim.x + threadIdx.x;
  if (i < EE) {
    atomicAdd(&degb[bei[EE + i]], 1.0f);
  } else if (i < 2 * EE) {
    atomicAdd(&degc[cei[EE + (i - EE)]], 1.0f);
  }
}

__global__ void k_finalize_deg(float* __restrict__ deg) {  // 2N entries -> dinv
  int i = blockIdx.x * blockDim.x + threadIdx.x;
  if (i < 2 * NN) deg[i] = rsqrtf(deg[i] + 1.0f);
}

// ---------------- encoder: relu(x@W_enc+b), accumulate BN stats ----------------
__global__ void k_encoder(const float* __restrict__ x, const float* __restrict__ W,
                          const float* __restrict__ b, float* __restrict__ A,
                          float* __restrict__ sum, float* __restrict__ sumsq) {
  int t = threadIdx.x;
  int c = t & 127, r = t >> 7;  // r in {0,1}
  int n0 = blockIdx.x * 64;
  float w0 = W[c], w1 = W[HH + c], w2 = W[2 * HH + c], bb = b[c];
  float ls = 0.f, lss = 0.f;
  for (int rr = r; rr < 64; rr += 2) {
    int n = n0 + rr;
    if (n < NN) {
      float v = fmaxf(x[n * 3] * w0 + x[n * 3 + 1] * w1 + x[n * 3 + 2] * w2 + bb, 0.f);
      A[(size_t)n * HH + c] = v;
      ls += v; lss += v * v;
    }
  }
  __shared__ float red[2][HH];
  red[r][c] = ls; __syncthreads();
  if (r == 0) atomicAdd(&sum[c], red[0][c] + red[1][c]);
  __syncthreads();
  red[r][c] = lss; __syncthreads();
  if (r == 0) atomicAdd(&sumsq[c], red[0][c] + red[1][c]);
}

// ---------------- BN finalize: scale/shift from sums ----------------
__global__ void k_bn_finalize(const float* __restrict__ sum, const float* __restrict__ sumsq,
                              const float* __restrict__ g, const float* __restrict__ be,
                              float* __restrict__ scale, float* __restrict__ shift, float invn) {
  int c = threadIdx.x;
  float m = sum[c] * invn;
  float v = fmaxf(sumsq[c] * invn - m * m, 0.f);
  float s = g[c] * rsqrtf(v + EPS_);
  scale[c] = s;
  shift[c] = be[c] - m * s;
}

__global__ void k_bn_apply(float* __restrict__ A, const float* __restrict__ scale,
                           const float* __restrict__ shift) {
  int i = blockIdx.x * 256 + threadIdx.x;
  if (i < NN * HH) {
    int c = i & 127;
    A[i] = A[i] * scale[c] + shift[c];
  }
}

// ---------------- GEMM: Y[N,H] = (relu?)(X) @ W[H,H] ----------------
template <int RELU>
__global__ void k_gemm_nh(const float* __restrict__ X, const float* __restrict__ W,
                          float* __restrict__ Y) {
  __shared__ float As[64][32];
  __shared__ float Ws[32][HH];
  int t = threadIdx.x;
  int tx = t & 31, ty = t >> 5;  // col = tx*4 .. +3 ; rows = ty*8 .. +7
  int row0 = blockIdx.x * 64;
  float acc[8][4];
#pragma unroll
  for (int i = 0; i < 8; ++i)
#pragma unroll
    for (int q = 0; q < 4; ++q) acc[i][q] = 0.f;

  for (int kc = 0; kc < HH; kc += 32) {
#pragma unroll
    for (int it = 0; it < 8; ++it) {  // stage A: 64x32
      int idx = t + it * 256;
      int rr = idx >> 5, kk = idx & 31;
      int row = row0 + rr;
      float v = (row < NN) ? X[(size_t)row * HH + kc + kk] : 0.f;
      if (RELU) v = fmaxf(v, 0.f);
      As[rr][kk] = v;
    }
#pragma unroll
    for (int it = 0; it < 16; ++it) {  // stage W: 32x128
      int idx = t + it * 256;
      int kk = idx >> 7, cc = idx & 127;
      Ws[kk][cc] = W[(size_t)(kc + kk) * HH + cc];
    }
    __syncthreads();
#pragma unroll
    for (int k = 0; k < 32; ++k) {
      float4 bv = *reinterpret_cast<float4*>(&Ws[k][tx * 4]);
#pragma unroll
      for (int i = 0; i < 8; ++i) {
        float a = As[ty * 8 + i][k];
        acc[i][0] += a * bv.x; acc[i][1] += a * bv.y;
        acc[i][2] += a * bv.z; acc[i][3] += a * bv.w;
      }
    }
    __syncthreads();
  }
#pragma unroll
  for (int i = 0; i < 8; ++i) {
    int row = row0 + ty * 8 + i;
    if (row < NN) {
      float4 v = make_float4(acc[i][0], acc[i][1], acc[i][2], acc[i][3]);
      *reinterpret_cast<float4*>(&Y[(size_t)row * HH + tx * 4]) = v;
    }
  }
}

// ---------------- GCN self-loop + bias: OUT (=|+=) bias + dinv^2 * C ----------------
__global__ void k_gcn_self(const float* __restrict__ C, const float* __restrict__ dinv,
                           const float* __restrict__ bias, float* __restrict__ OUT, int add) {
  int i = blockIdx.x * 256 + threadIdx.x;
  if (i >= NN * HH) return;
  int n = i >> 7, c = i & 127;
  float d = dinv[n];
  float v = bias[c] + d * d * C[i];
  if (add) OUT[i] += v; else OUT[i] = v;
}

// ---------------- GCN edge scatter: OUT[dst] += dinv[s]*dinv[d]*C[src] ----------------
__global__ void k_scatter(const float* __restrict__ C, const int* __restrict__ ei,
                          const float* __restrict__ dinv, float* __restrict__ OUT) {
  int t = threadIdx.x;
  int e = blockIdx.x * 2 + (t >> 7);
  int c = t & 127;
  if (e >= EE) return;
  int s = ei[e], d = ei[EE + e];
  float w = dinv[s] * dinv[d];
  atomicAdd(&OUT[(size_t)d * HH + c], w * C[(size_t)s * HH + c]);
}

// ---------------- bf16 conversion helpers ----------------
__global__ void k_h2_to_bf16(const float* __restrict__ A, __hip_bfloat16* __restrict__ h2b) {
  int i = blockIdx.x * 256 + threadIdx.x;
  if (i < NN * HH) h2b[i] = __float2bfloat16(A[i]);
}

// W1 [256][128] row-major fp32 -> W1t [128][256] bf16 (col-major over k)
__global__ void k_w1t_bf16(const float* __restrict__ W1, __hip_bfloat16* __restrict__ Wt) {
  int i = blockIdx.x * 256 + threadIdx.x;
  if (i < 256 * 128) {
    int c = i & 127, k = i >> 7;
    Wt[(size_t)c * 256 + k] = __float2bfloat16(W1[i]);
  }
}

// ---------------- edge MLP via MFMA ----------------
// t = relu(concat(h2[s],h2[d]) @ W1 + b1)   [E x 128], K = 256
// PASS2=0: accumulate BN stats of t.  PASS2=1: recompute, BN-apply, out = t_hat@W2 + b2.
// Block: 64 edges, 4 waves in 2x2 grid (wave = 32 rows x 64 cols), full K in LDS.
template <int PASS2>
__global__ __launch_bounds__(256) void k_edge_mlp_mfma(
    const __hip_bfloat16* __restrict__ h2b, const int* __restrict__ ei,
    const __hip_bfloat16* __restrict__ W1t, const float* __restrict__ b1,
    float* __restrict__ sum, float* __restrict__ sumsq,
    const float* __restrict__ scale, const float* __restrict__ shift,
    const float* __restrict__ W2, const float* __restrict__ b2,
    float* __restrict__ out) {
  // A_s: [64][264] bf16 (pad +8 bf16 -> row stride 528B = 132 dwords, breaks bank conflict)
  // reused in PASS2 epilogue as tS: [64][132] f32 (same 33792 bytes)
  __shared__ char smem[64 * 264 * 2];
  __shared__ float redS[HH], redQ[HH];
  short* As = (short*)smem;
  const int t = threadIdx.x;
  const int e0 = blockIdx.x * 64;

  // ---- stage gathered A tile: 64 rows x 256 bf16 (cols 0-127 = h2[src], 128-255 = h2[dst])
#pragma unroll
  for (int i = 0; i < 8; ++i) {
    int idx = i * 256 + t;               // 2048 chunks of 8 bf16
    int r = idx >> 5, kc = (idx & 31) * 8;
    int eg = e0 + r; if (eg > EE - 1) eg = EE - 1;
    int row = (kc < HH) ? ei[eg] : ei[EE + eg];
    const short* src = (const short*)&h2b[(size_t)row * HH + (kc & 127)];
    *(bf16x8*)&As[r * 264 + kc] = *(const bf16x8*)src;
  }
  if (!PASS2) {
    if (t < HH) { redS[t] = 0.f; redQ[t] = 0.f; }
  }
  __syncthreads();

  const int l = t & 63, wid = t >> 6;
  const int wm = wid >> 1, wn = wid & 1;    // 2x2 wave grid
  const int lr = l & 15, lg = l >> 4;

  f32x4 acc[2][4];
#pragma unroll
  for (int mf = 0; mf < 2; ++mf)
#pragma unroll
    for (int nf = 0; nf < 4; ++nf) acc[mf][nf] = (f32x4){0.f, 0.f, 0.f, 0.f};

#pragma unroll
  for (int ks = 0; ks < 8; ++ks) {          // K = 8 x 32
    bf16x8 a0 = *(bf16x8*)&As[(wm * 32 + lr) * 264 + ks * 32 + lg * 8];
    bf16x8 a1 = *(bf16x8*)&As[(wm * 32 + 16 + lr) * 264 + ks * 32 + lg * 8];
#pragma unroll
    for (int nf = 0; nf < 4; ++nf) {
      int col = wn * 64 + nf * 16 + lr;
      bf16x8 b = *(const bf16x8*)&W1t[(size_t)col * 256 + ks * 32 + lg * 8];
      acc[0][nf] = __builtin_amdgcn_mfma_f32_16x16x32_bf16(a0, b, acc[0][nf], 0, 0, 0);
      acc[1][nf] = __builtin_amdgcn_mfma_f32_16x16x32_bf16(a1, b, acc[1][nf], 0, 0, 0);
    }
  }

  // C/D layout: col = lane&15 (per nf frag), row = (lane>>4)*4 + j
  if (!PASS2) {
#pragma unroll
    for (int nf = 0; nf < 4; ++nf) {
      int col = wn * 64 + nf * 16 + lr;
      float b1c = b1[col];
      float s = 0.f, q = 0.f;
#pragma unroll
      for (int mf = 0; mf < 2; ++mf)
#pragma unroll
        for (int j = 0; j < 4; ++j) {
          int row = e0 + wm * 32 + mf * 16 + lg * 4 + j;
          if (row < EE) {
            float v = fmaxf(acc[mf][nf][j] + b1c, 0.f);
            s += v; q += v * v;
          }
        }
      atomicAdd(&redS[col], s);
      atomicAdd(&redQ[col], q);
    }
    __syncthreads();
    if (t < HH) {
      atomicAdd(&sum[t], redS[t]);
      atomicAdd(&sumsq[t], redQ[t]);
    }
  } else {
    __syncthreads();   // everyone done reading As -> reuse as tS
    float* tS = (float*)smem;  // [64][132]
#pragma unroll
    for (int nf = 0; nf < 4; ++nf) {
      int col = wn * 64 + nf * 16 + lr;
      float b1c = b1[col], sc = scale[col], sh = shift[col];
#pragma unroll
      for (int mf = 0; mf < 2; ++mf)
#pragma unroll
        for (int j = 0; j < 4; ++j) {
          float v = fmaxf(acc[mf][nf][j] + b1c, 0.f) * sc + sh;
          tS[(wm * 32 + mf * 16 + lg * 4 + j) * 132 + col] = v;
        }
    }
    __syncthreads();
    if (t < 2 * 64) {
      int row = t >> 1, j = t & 1;
      float s = 0.f;
      const float4* trow = (const float4*)&tS[row * 132];
#pragma unroll
      for (int c4 = 0; c4 < 32; ++c4) {
        float4 v = trow[c4];
        s += v.x * W2[(c4 * 4 + 0) * 2 + j] + v.y * W2[(c4 * 4 + 1) * 2 + j]
           + v.z * W2[(c4 * 4 + 2) * 2 + j] + v.w * W2[(c4 * 4 + 3) * 2 + j];
      }
      int eg = e0 + row;
      if (eg < EE) out[(size_t)eg * 2 + j] = s + b2[j];
    }
  }
}

// ---------------- edge types: zeros(E) then ones(E), as float ----------------
__global__ void k_edge_types(float* __restrict__ out) {
  int i = blockIdx.x * 256 + threadIdx.x;
  if (i < 2 * EE) out[(size_t)2 * EE * 2 + i] = (i < EE) ? 0.0f : 1.0f;
}

extern "C" void kernel_launch(void* const* d_in, const int* in_sizes, int n_in,
                              void* d_out, int out_size, void* d_ws, size_t ws_size,
                              hipStream_t stream) {
  const float* x      = (const float*)d_in[0];
  const int*   bei    = (const int*)d_in[1];
  const int*   cei    = (const int*)d_in[2];
  const float* W_enc  = (const float*)d_in[3];
  const float* b_enc  = (const float*)d_in[4];
  const float* g_enc  = (const float*)d_in[5];
  const float* be_enc = (const float*)d_in[6];
  const float* W1b = (const float*)d_in[7];  const float* b1b = (const float*)d_in[8];
  const float* W1c = (const float*)d_in[9];  const float* b1c = (const float*)d_in[10];
  const float* W2b = (const float*)d_in[11]; const float* b2b = (const float*)d_in[12];
  const float* W2c = (const float*)d_in[13]; const float* b2c = (const float*)d_in[14];
  const float* Wbp1 = (const float*)d_in[15]; const float* bbp1 = (const float*)d_in[16];
  const float* gbp  = (const float*)d_in[17]; const float* bebp = (const float*)d_in[18];
  const float* Wbp2 = (const float*)d_in[19]; const float* bbp2 = (const float*)d_in[20];
  const float* Wcp1 = (const float*)d_in[21]; const float* bcp1 = (const float*)d_in[22];
  const float* gcp  = (const float*)d_in[23]; const float* becp = (const float*)d_in[24];
  const float* Wcp2 = (const float*)d_in[25]; const float* bcp2 = (const float*)d_in[26];
  float* out = (float*)d_out;

  float* ws = (float*)d_ws;
  float* A = ws;                         // h, later h2   [N*H]
  float* B = A + (size_t)NN * HH;        // h1            [N*H]
  float* C = B + (size_t)NN * HH;        // xw tmp; later bf16 h2 + W1t   [N*H]
  float* degb = C + (size_t)NN * HH;     // dinv beam     [N]
  float* degc = degb + NN;               // dinv col      [N]
  float* st   = degc + NN;               // sum,sumsq,scale,shift [4*H]
  float* s_sum = st, *s_sq = st + HH, *s_scale = st + 2 * HH, *s_shift = st + 3 * HH;

  hipMemsetAsync(degb, 0, sizeof(float) * 2 * NN, stream);
  hipMemsetAsync(st, 0, sizeof(float) * 2 * HH, stream);
  k_count_deg<<<(2 * EE + 255) / 256, 256, 0, stream>>>(bei, cei, degb, degc);
  k_finalize_deg<<<(2 * NN + 255) / 256, 256, 0, stream>>>(degb);

  // encoder + BN
  k_encoder<<<(NN + 63) / 64, 256, 0, stream>>>(x, W_enc, b_enc, A, s_sum, s_sq);
  k_bn_finalize<<<1, 128, 0, stream>>>(s_sum, s_sq, g_enc, be_enc, s_scale, s_shift, 1.0f / NN);
  k_bn_apply<<<(NN * HH + 255) / 256, 256, 0, stream>>>(A, s_scale, s_shift);

  int gblk = (NN + 63) / 64;
  int eblk = (NN * HH + 255) / 256;
  int sblk = (EE + 1) / 2;
  // GCN layer 1: h1 = relu(gcn_b(h) + gcn_c(h)) ; relu applied on read in layer 2
  k_gemm_nh<0><<<gblk, 256, 0, stream>>>(A, W1b, C);
  k_gcn_self<<<eblk, 256, 0, stream>>>(C, degb, b1b, B, 0);
  k_scatter<<<sblk, 256, 0, stream>>>(C, bei, degb, B);
  k_gemm_nh<0><<<gblk, 256, 0, stream>>>(A, W1c, C);
  k_gcn_self<<<eblk, 256, 0, stream>>>(C, degc, b1c, B, 1);
  k_scatter<<<sblk, 256, 0, stream>>>(C, cei, degc, B);
  // GCN layer 2: h2 = gcn_b(relu(h1)) + gcn_c(relu(h1))  -> into A
  k_gemm_nh<1><<<gblk, 256, 0, stream>>>(B, W2b, C);
  k_gcn_self<<<eblk, 256, 0, stream>>>(C, degb, b2b, A, 0);
  k_scatter<<<sblk, 256, 0, stream>>>(C, bei, degb, A);
  k_gemm_nh<1><<<gblk, 256, 0, stream>>>(B, W2c, C);
  k_gcn_self<<<eblk, 256, 0, stream>>>(C, degc, b2c, A, 1);
  k_scatter<<<sblk, 256, 0, stream>>>(C, cei, degc, A);

  // ---- edge predictors (MFMA path). bf16 buffers alias the now-dead C buffer.
  __hip_bfloat16* h2b  = (__hip_bfloat16*)C;              // 12.8 MB of C's 25.6 MB
  __hip_bfloat16* W1bt = h2b + (size_t)NN * HH;           // 64 KB
  __hip_bfloat16* W1ct = W1bt + 256 * 128;                // 64 KB
  k_h2_to_bf16<<<(NN * HH + 255) / 256, 256, 0, stream>>>(A, h2b);
  k_w1t_bf16<<<(256 * 128 + 255) / 256, 256, 0, stream>>>(Wbp1, W1bt);
  k_w1t_bf16<<<(256 * 128 + 255) / 256, 256, 0, stream>>>(Wcp1, W1ct);

  int mblk = (EE + 63) / 64;
  hipMemsetAsync(st, 0, sizeof(float) * 2 * HH, stream);
  k_edge_mlp_mfma<0><<<mblk, 256, 0, stream>>>(h2b, bei, W1bt, bbp1, s_sum, s_sq,
                                               nullptr, nullptr, nullptr, nullptr, nullptr);
  k_bn_finalize<<<1, 128, 0, stream>>>(s_sum, s_sq, gbp, bebp, s_scale, s_shift, 1.0f / EE);
  k_edge_mlp_mfma<1><<<mblk, 256, 0, stream>>>(h2b, bei, W1bt, bbp1, nullptr, nullptr,
                                               s_scale, s_shift, Wbp2, bbp2, out);
  hipMemsetAsync(st, 0, sizeof(float) * 2 * HH, stream);
  k_edge_mlp_mfma<0><<<mblk, 256, 0, stream>>>(h2b, cei, W1ct, bcp1, s_sum, s_sq,
                                               nullptr, nullptr, nullptr, nullptr, nullptr);
  k_bn_finalize<<<1, 128, 0, stream>>>(s_sum, s_sq, gcp, becp, s_scale, s_shift, 1.0f / EE);
  k_edge_mlp_mfma<1><<<mblk, 256, 0, stream>>>(h2b, cei, W1ct, bcp1, nullptr, nullptr,
                                               s_scale, s_shift, Wcp2, bcp2, out + (size_t)2 * EE);

  k_edge_types<<<(2 * EE + 255) / 256, 256, 0, stream>>>(out);
}

// Round 3
// 1082.577 us; speedup vs baseline: 3.2264x; 1.1354x over previous
//
#include <hip/hip_runtime.h>
#include <hip/hip_bf16.h>

#define NN 50000
#define EE 250000
#define HH 128
#define EPS_ 1e-5f

typedef __attribute__((ext_vector_type(8))) short bf16x8;
typedef __attribute__((ext_vector_type(4))) float f32x4;

__device__ __forceinline__ float bf2f(ushort u) {
  union { unsigned int i; float f; } x; x.i = ((unsigned int)u) << 16; return x.f;
}
__device__ __forceinline__ ushort f2bf(float f) {
  union { float f; unsigned int i; } x; x.f = f;
  unsigned int r = (x.i + 0x7fffu + ((x.i >> 16) & 1u)) >> 16;  // RNE, finite inputs
  return (ushort)r;
}

// ---------------- degree / CSR build ----------------
__global__ void k_count(const int* __restrict__ bei, const int* __restrict__ cei,
                        int* __restrict__ cntb, int* __restrict__ cntc) {
  int i = blockIdx.x * blockDim.x + threadIdx.x;
  if (i < EE) atomicAdd(&cntb[bei[EE + i]], 1);
  else if (i < 2 * EE) atomicAdd(&cntc[cei[EE + (i - EE)]], 1);
}

__global__ void k_dinv(const int* __restrict__ cnt, float* __restrict__ dinv) {
  int i = blockIdx.x * blockDim.x + threadIdx.x;  // 2N: [cntb|cntc] -> [dinvb|dinvc]
  if (i < 2 * NN) dinv[i] = rsqrtf((float)cnt[i] + 1.0f);
}

__global__ void k_scan(const int* __restrict__ cntb, int* __restrict__ offb, int* __restrict__ curb,
                       const int* __restrict__ cntc, int* __restrict__ offc, int* __restrict__ curc) {
  __shared__ int part[1024];
  const int t = threadIdx.x;
  const int CH = (NN + 1023) / 1024;  // 49
  for (int rel = 0; rel < 2; ++rel) {
    const int* c_ = rel ? cntc : cntb;
    int* o_ = rel ? offc : offb;
    int* u_ = rel ? curc : curb;
    int base = t * CH, s = 0;
    for (int j = 0; j < CH; ++j) { int idx = base + j; if (idx < NN) s += c_[idx]; }
    part[t] = s;
    __syncthreads();
    for (int ofs = 1; ofs < 1024; ofs <<= 1) {
      int v = (t >= ofs) ? part[t - ofs] : 0;
      __syncthreads();
      part[t] += v;
      __syncthreads();
    }
    int run = (t == 0) ? 0 : part[t - 1];
    for (int j = 0; j < CH; ++j) {
      int idx = base + j;
      if (idx < NN) { o_[idx] = run; u_[idx] = run; run += c_[idx]; }
    }
    __syncthreads();
  }
}

__global__ void k_fill(const int* __restrict__ bei, const int* __restrict__ cei,
                       int* __restrict__ curb, int* __restrict__ listb,
                       int* __restrict__ curc, int* __restrict__ listc) {
  int i = blockIdx.x * blockDim.x + threadIdx.x;
  if (i < EE) {
    int dst = bei[EE + i];
    int p = atomicAdd(&curb[dst], 1);
    listb[p] = bei[i];
  } else if (i < 2 * EE) {
    int e = i - EE;
    int dst = cei[EE + e];
    int p = atomicAdd(&curc[dst], 1);
    listc[p] = cei[e];
  }
}

// ---------------- encoder: relu(x@W_enc+b) -> bf16, accumulate BN stats ----------------
__global__ void k_encoder_bf(const float* __restrict__ x, const float* __restrict__ W,
                             const float* __restrict__ b, ushort* __restrict__ hb,
                             float* __restrict__ sum, float* __restrict__ sumsq) {
  int t = threadIdx.x;
  int c = t & 127, r = t >> 7;
  int n0 = blockIdx.x * 64;
  float w0 = W[c], w1 = W[HH + c], w2 = W[2 * HH + c], bb = b[c];
  float ls = 0.f, lss = 0.f;
  for (int rr = r; rr < 64; rr += 2) {
    int n = n0 + rr;
    if (n < NN) {
      float v = fmaxf(x[n * 3] * w0 + x[n * 3 + 1] * w1 + x[n * 3 + 2] * w2 + bb, 0.f);
      ushort u = f2bf(v);
      hb[(size_t)n * HH + c] = u;
      float vr = bf2f(u);          // stats on the rounded value (self-consistent BN)
      ls += vr; lss += vr * vr;
    }
  }
  __shared__ float red[2][HH];
  red[r][c] = ls; __syncthreads();
  if (r == 0) atomicAdd(&sum[c], red[0][c] + red[1][c]);
  __syncthreads();
  red[r][c] = lss; __syncthreads();
  if (r == 0) atomicAdd(&sumsq[c], red[0][c] + red[1][c]);
}

__global__ void k_bn_finalize(const float* __restrict__ sum, const float* __restrict__ sumsq,
                              const float* __restrict__ g, const float* __restrict__ be,
                              float* __restrict__ scale, float* __restrict__ shift, float invn) {
  int c = threadIdx.x;
  float m = sum[c] * invn;
  float v = fmaxf(sumsq[c] * invn - m * m, 0.f);
  float s = g[c] * rsqrtf(v + EPS_);
  scale[c] = s;
  shift[c] = be[c] - m * s;
}

__global__ void k_bn_apply_bf(ushort* __restrict__ hb, const float* __restrict__ scale,
                              const float* __restrict__ shift) {
  int i = blockIdx.x * 256 + threadIdx.x;  // i over N*H/4
  if (i * 4 < NN * HH) {
    int base = i * 4, c0 = base & 127;
    ushort4 u = *(ushort4*)&hb[base];
    u.x = f2bf(bf2f(u.x) * scale[c0] + shift[c0]);
    u.y = f2bf(bf2f(u.y) * scale[c0 + 1] + shift[c0 + 1]);
    u.z = f2bf(bf2f(u.z) * scale[c0 + 2] + shift[c0 + 2]);
    u.w = f2bf(bf2f(u.w) * scale[c0 + 3] + shift[c0 + 3]);
    *(ushort4*)&hb[base] = u;
  }
}

// ---------------- weight transposes to bf16 ----------------
__global__ void k_wt128_all(const float* __restrict__ s0, const float* __restrict__ s1,
                            const float* __restrict__ s2, const float* __restrict__ s3,
                            ushort* __restrict__ d0, ushort* __restrict__ d1,
                            ushort* __restrict__ d2, ushort* __restrict__ d3) {
  int i = blockIdx.x * 256 + threadIdx.x;
  if (i < 4 * 128 * 128) {
    int sel = i >> 14, loc = i & 16383;
    int k = loc >> 7, c = loc & 127;
    const float* s = sel == 0 ? s0 : sel == 1 ? s1 : sel == 2 ? s2 : s3;
    ushort* d = sel == 0 ? d0 : sel == 1 ? d1 : sel == 2 ? d2 : d3;
    d[c * 128 + k] = f2bf(s[loc]);
  }
}

__global__ void k_wt256_all(const float* __restrict__ s0, const float* __restrict__ s1,
                            ushort* __restrict__ d0, ushort* __restrict__ d1) {
  int i = blockIdx.x * 256 + threadIdx.x;
  if (i < 2 * 256 * 128) {
    int sel = i >> 15, loc = i & 32767;
    int k = loc >> 7, c = loc & 127;
    const float* s = sel ? s1 : s0;
    ushort* d = sel ? d1 : d0;
    d[c * 256 + k] = f2bf(s[loc]);
  }
}

// ---------------- bf16 GEMM: Y[N,128] = X[N,128] @ W  (Wt is [c][k] bf16) ----------------
__global__ __launch_bounds__(256) void k_gemm_bf(const ushort* __restrict__ X,
                                                 const ushort* __restrict__ Wt,
                                                 ushort* __restrict__ Y) {
  const int t = threadIdx.x;
  const int l = t & 63, wid = t >> 6;
  const int wm = wid >> 1, wn = wid & 1;
  const int lr = l & 15, lg = l >> 4;
  const int n0 = blockIdx.x * 64;
  f32x4 acc[2][4];
#pragma unroll
  for (int mf = 0; mf < 2; ++mf)
#pragma unroll
    for (int nf = 0; nf < 4; ++nf) acc[mf][nf] = (f32x4){0.f, 0.f, 0.f, 0.f};
  int r0 = n0 + wm * 32 + lr;
  int rA = min(r0, NN - 1), rB = min(r0 + 16, NN - 1);
  const ushort* xa = X + (size_t)rA * HH + lg * 8;
  const ushort* xb = X + (size_t)rB * HH + lg * 8;
#pragma unroll
  for (int ks = 0; ks < 4; ++ks) {
    bf16x8 a0 = *(const bf16x8*)(xa + ks * 32);
    bf16x8 a1 = *(const bf16x8*)(xb + ks * 32);
#pragma unroll
    for (int nf = 0; nf < 4; ++nf) {
      int col = wn * 64 + nf * 16 + lr;
      bf16x8 b = *(const bf16x8*)(Wt + col * 128 + ks * 32 + lg * 8);
      acc[0][nf] = __builtin_amdgcn_mfma_f32_16x16x32_bf16(a0, b, acc[0][nf], 0, 0, 0);
      acc[1][nf] = __builtin_amdgcn_mfma_f32_16x16x32_bf16(a1, b, acc[1][nf], 0, 0, 0);
    }
  }
#pragma unroll
  for (int mf = 0; mf < 2; ++mf)
#pragma unroll
    for (int nf = 0; nf < 4; ++nf) {
      int col = wn * 64 + nf * 16 + lr;
#pragma unroll
      for (int j = 0; j < 4; ++j) {
        int row = n0 + wm * 32 + mf * 16 + lg * 4 + j;
        if (row < NN) Y[(size_t)row * HH + col] = f2bf(acc[mf][nf][j]);
      }
    }
}

// ---------------- fused aggregation: bias+self+both relations (+relu) -> bf16 ----------------
template <int RELU>
__global__ void k_agg(const ushort* __restrict__ xwb, const ushort* __restrict__ xwc,
                      const float* __restrict__ dinvb, const float* __restrict__ dinvc,
                      const int* __restrict__ offb, const int* __restrict__ cntb,
                      const int* __restrict__ listb,
                      const int* __restrict__ offc, const int* __restrict__ cntc,
                      const int* __restrict__ listc,
                      const float* __restrict__ bb, const float* __restrict__ bc,
                      ushort* __restrict__ out) {
  int t = threadIdx.x;
  int n = blockIdx.x * 2 + (t >> 7);
  int c = t & 127;
  if (n >= NN) return;
  float dnb = dinvb[n], dnc = dinvc[n];
  float acc = bb[c] + bc[c] + dnb * dnb * bf2f(xwb[(size_t)n * HH + c])
                            + dnc * dnc * bf2f(xwc[(size_t)n * HH + c]);
  int o = offb[n], e = o + cntb[n];
  float s = 0.f;
  for (; o < e; ++o) { int src = listb[o]; s += dinvb[src] * bf2f(xwb[(size_t)src * HH + c]); }
  acc += dnb * s;
  o = offc[n]; e = o + cntc[n];
  s = 0.f;
  for (; o < e; ++o) { int src = listc[o]; s += dinvc[src] * bf2f(xwc[(size_t)src * HH + c]); }
  acc += dnc * s;
  if (RELU) acc = fmaxf(acc, 0.f);
  out[(size_t)n * HH + c] = f2bf(acc);
}

// ---------------- edge MLP: no-LDS direct-gather MFMA ----------------
// t = relu(concat(h2[s],h2[d]) @ W1 + b1)  [E x 128], K=256
// PASS2=0: BN stats.  PASS2=1: recompute, BN-apply, out = t_hat@W2 + b2.
template <int PASS2>
__global__ __launch_bounds__(256) void k_edge_mlp2(
    const ushort* __restrict__ h2b, const int* __restrict__ ei,
    const ushort* __restrict__ W1t, const float* __restrict__ b1,
    float* __restrict__ gsum, float* __restrict__ gsq,
    const float* __restrict__ scale, const float* __restrict__ shift,
    const float* __restrict__ W2, const float* __restrict__ b2,
    float* __restrict__ out) {
  __shared__ float redA[HH];
  __shared__ float redB[HH];
  const int t = threadIdx.x;
  const int l = t & 63, wid = t >> 6;
  const int wm = wid >> 1, wn = wid & 1;
  const int lr = l & 15, lg = l >> 4;
  const int e0 = blockIdx.x * 64;
  if (!PASS2) {
    if (t < HH) { redA[t] = 0.f; redB[t] = 0.f; }
  } else {
    if (t < HH) redA[t] = 0.f;  // reused as red2[64][2]
  }
  __syncthreads();

  int r0 = e0 + wm * 32 + lr;
  int rA = min(r0, EE - 1), rB = min(r0 + 16, EE - 1);
  int sA = ei[rA], dA = ei[EE + rA];
  int sB = ei[rB], dB = ei[EE + rB];

  f32x4 acc[2][4];
#pragma unroll
  for (int mf = 0; mf < 2; ++mf)
#pragma unroll
    for (int nf = 0; nf < 4; ++nf) acc[mf][nf] = (f32x4){0.f, 0.f, 0.f, 0.f};

#pragma unroll
  for (int ks = 0; ks < 8; ++ks) {
    int rowA = (ks < 4) ? sA : dA;
    int rowB = (ks < 4) ? sB : dB;
    int ko = (ks & 3) * 32 + lg * 8;
    bf16x8 a0 = *(const bf16x8*)(h2b + (size_t)rowA * HH + ko);
    bf16x8 a1 = *(const bf16x8*)(h2b + (size_t)rowB * HH + ko);
#pragma unroll
    for (int nf = 0; nf < 4; ++nf) {
      int col = wn * 64 + nf * 16 + lr;
      bf16x8 b = *(const bf16x8*)(W1t + col * 256 + ks * 32 + lg * 8);
      acc[0][nf] = __builtin_amdgcn_mfma_f32_16x16x32_bf16(a0, b, acc[0][nf], 0, 0, 0);
      acc[1][nf] = __builtin_amdgcn_mfma_f32_16x16x32_bf16(a1, b, acc[1][nf], 0, 0, 0);
    }
  }

  if (!PASS2) {
#pragma unroll
    for (int nf = 0; nf < 4; ++nf) {
      int col = wn * 64 + nf * 16 + lr;
      float b1c = b1[col];
      float s = 0.f, q = 0.f;
#pragma unroll
      for (int mf = 0; mf < 2; ++mf)
#pragma unroll
        for (int j = 0; j < 4; ++j) {
          int row = e0 + wm * 32 + mf * 16 + lg * 4 + j;
          if (row < EE) {
            float v = fmaxf(acc[mf][nf][j] + b1c, 0.f);
            s += v; q += v * v;
          }
        }
      atomicAdd(&redA[col], s);
      atomicAdd(&redB[col], q);
    }
    __syncthreads();
    if (t < HH) {
      atomicAdd(&gsum[t], redA[t]);
      atomicAdd(&gsq[t], redB[t]);
    }
  } else {
    float p0[2][4], p1[2][4];
#pragma unroll
    for (int mf = 0; mf < 2; ++mf)
#pragma unroll
      for (int j = 0; j < 4; ++j) { p0[mf][j] = 0.f; p1[mf][j] = 0.f; }
#pragma unroll
    for (int nf = 0; nf < 4; ++nf) {
      int col = wn * 64 + nf * 16 + lr;
      float b1c = b1[col], sc = scale[col], sh = shift[col];
      float w20 = W2[col * 2], w21 = W2[col * 2 + 1];
#pragma unroll
      for (int mf = 0; mf < 2; ++mf)
#pragma unroll
        for (int j = 0; j < 4; ++j) {
          float v = fmaxf(acc[mf][nf][j] + b1c, 0.f) * sc + sh;
          p0[mf][j] += v * w20;
          p1[mf][j] += v * w21;
        }
    }
    // reduce over the 16 lanes of each lg-group (lanes lg*16+lr are contiguous)
#pragma unroll
    for (int m = 8; m >= 1; m >>= 1) {
#pragma unroll
      for (int mf = 0; mf < 2; ++mf)
#pragma unroll
        for (int j = 0; j < 4; ++j) {
          p0[mf][j] += __shfl_xor(p0[mf][j], m, 64);
          p1[mf][j] += __shfl_xor(p1[mf][j], m, 64);
        }
    }
    float* red2 = redA;  // [64][2]
    if (lr == 0) {
#pragma unroll
      for (int mf = 0; mf < 2; ++mf)
#pragma unroll
        for (int j = 0; j < 4; ++j) {
          int row = wm * 32 + mf * 16 + lg * 4 + j;
          atomicAdd(&red2[row * 2 + 0], p0[mf][j]);
          atomicAdd(&red2[row * 2 + 1], p1[mf][j]);
        }
    }
    __syncthreads();
    if (t < 128) {
      int row = t >> 1, j = t & 1;
      int eg = e0 + row;
      if (eg < EE) out[(size_t)eg * 2 + j] = red2[t] + b2[j];
    }
  }
}

// ---------------- edge types ----------------
__global__ void k_edge_types(float* __restrict__ out) {
  int i = blockIdx.x * 256 + threadIdx.x;
  if (i < 2 * EE) out[(size_t)2 * EE * 2 + i] = (i < EE) ? 0.0f : 1.0f;
}

extern "C" void kernel_launch(void* const* d_in, const int* in_sizes, int n_in,
                              void* d_out, int out_size, void* d_ws, size_t ws_size,
                              hipStream_t stream) {
  const float* x      = (const float*)d_in[0];
  const int*   bei    = (const int*)d_in[1];
  const int*   cei    = (const int*)d_in[2];
  const float* W_enc  = (const float*)d_in[3];
  const float* b_enc  = (const float*)d_in[4];
  const float* g_enc  = (const float*)d_in[5];
  const float* be_enc = (const float*)d_in[6];
  const float* W1b = (const float*)d_in[7];  const float* b1b = (const float*)d_in[8];
  const float* W1c = (const float*)d_in[9];  const float* b1c = (const float*)d_in[10];
  const float* W2b = (const float*)d_in[11]; const float* b2b = (const float*)d_in[12];
  const float* W2c = (const float*)d_in[13]; const float* b2c = (const float*)d_in[14];
  const float* Wbp1 = (const float*)d_in[15]; const float* bbp1 = (const float*)d_in[16];
  const float* gbp  = (const float*)d_in[17]; const float* bebp = (const float*)d_in[18];
  const float* Wbp2 = (const float*)d_in[19]; const float* bbp2 = (const float*)d_in[20];
  const float* Wcp1 = (const float*)d_in[21]; const float* bcp1 = (const float*)d_in[22];
  const float* gcp  = (const float*)d_in[23]; const float* becp = (const float*)d_in[24];
  const float* Wcp2 = (const float*)d_in[25]; const float* bcp2 = (const float*)d_in[26];
  float* out = (float*)d_out;

  // ---- workspace layout (~55 MB) ----
  ushort* hb   = (ushort*)d_ws;                 // h (bf16); later h2  [N*H]
  ushort* h1b  = hb + (size_t)NN * HH;          // h1 bf16
  ushort* xwb  = h1b + (size_t)NN * HH;         // per-relation x@W bf16
  ushort* xwc  = xwb + (size_t)NN * HH;
  ushort* Wt1b = xwc + (size_t)NN * HH;         // 128x128 transposed weights (bf16)
  ushort* Wt1c = Wt1b + 128 * 128;
  ushort* Wt2b = Wt1c + 128 * 128;
  ushort* Wt2c = Wt2b + 128 * 128;
  ushort* Wmb  = Wt2c + 128 * 128;              // MLP W1^T [128][256]
  ushort* Wmc  = Wmb + 256 * 128;
  float* dinv  = (float*)(Wmc + 256 * 128);     // dinvb[N], dinvc[N]
  float* dinvb = dinv, *dinvc = dinv + NN;
  float* st    = dinvc + NN;                    // sum, sumsq, scale, shift [4*H]
  float* s_sum = st, *s_sq = st + HH, *s_scale = st + 2 * HH, *s_shift = st + 3 * HH;
  int* cnt  = (int*)(st + 4 * HH);              // cntb[N], cntc[N]
  int* cntb = cnt, *cntc = cnt + NN;
  int* offb = cntc + NN; int* offc = offb + NN;
  int* curb = offc + NN; int* curc = curb + NN;
  int* listb = curc + NN; int* listc = listb + EE;

  // ---- degrees + CSR ----
  hipMemsetAsync(cnt, 0, sizeof(int) * 2 * NN, stream);
  hipMemsetAsync(st, 0, sizeof(float) * 2 * HH, stream);
  k_count<<<(2 * EE + 255) / 256, 256, 0, stream>>>(bei, cei, cntb, cntc);
  k_dinv<<<(2 * NN + 255) / 256, 256, 0, stream>>>(cnt, dinv);
  k_scan<<<1, 1024, 0, stream>>>(cntb, offb, curb, cntc, offc, curc);
  k_fill<<<(2 * EE + 255) / 256, 256, 0, stream>>>(bei, cei, curb, listb, curc, listc);

  // ---- encoder + BN -> hb (bf16) ----
  k_encoder_bf<<<(NN + 63) / 64, 256, 0, stream>>>(x, W_enc, b_enc, hb, s_sum, s_sq);
  k_bn_finalize<<<1, 128, 0, stream>>>(s_sum, s_sq, g_enc, be_enc, s_scale, s_shift, 1.0f / NN);
  k_bn_apply_bf<<<(NN * HH / 4 + 255) / 256, 256, 0, stream>>>(hb, s_scale, s_shift);

  // ---- weight transposes ----
  k_wt128_all<<<(4 * 16384 + 255) / 256, 256, 0, stream>>>(W1b, W1c, W2b, W2c,
                                                           Wt1b, Wt1c, Wt2b, Wt2c);
  k_wt256_all<<<(2 * 32768 + 255) / 256, 256, 0, stream>>>(Wbp1, Wcp1, Wmb, Wmc);

  int gblk = (NN + 63) / 64;
  int ablk = (NN + 1) / 2;
  // ---- GCN layer 1: h1 = relu(agg_b + agg_c) ----
  k_gemm_bf<<<gblk, 256, 0, stream>>>(hb, Wt1b, xwb);
  k_gemm_bf<<<gblk, 256, 0, stream>>>(hb, Wt1c, xwc);
  k_agg<1><<<ablk, 256, 0, stream>>>(xwb, xwc, dinvb, dinvc, offb, cntb, listb,
                                     offc, cntc, listc, b1b, b1c, h1b);
  // ---- GCN layer 2: h2 (into hb slot) ----
  k_gemm_bf<<<gblk, 256, 0, stream>>>(h1b, Wt2b, xwb);
  k_gemm_bf<<<gblk, 256, 0, stream>>>(h1b, Wt2c, xwc);
  k_agg<0><<<ablk, 256, 0, stream>>>(xwb, xwc, dinvb, dinvc, offb, cntb, listb,
                                     offc, cntc, listc, b2b, b2c, hb);

  // ---- edge predictors ----
  int mblk = (EE + 63) / 64;
  hipMemsetAsync(st, 0, sizeof(float) * 2 * HH, stream);
  k_edge_mlp2<0><<<mblk, 256, 0, stream>>>(hb, bei, Wmb, bbp1, s_sum, s_sq,
                                           nullptr, nullptr, nullptr, nullptr, nullptr);
  k_bn_finalize<<<1, 128, 0, stream>>>(s_sum, s_sq, gbp, bebp, s_scale, s_shift, 1.0f / EE);
  k_edge_mlp2<1><<<mblk, 256, 0, stream>>>(hb, bei, Wmb, bbp1, nullptr, nullptr,
                                           s_scale, s_shift, Wbp2, bbp2, out);
  hipMemsetAsync(st, 0, sizeof(float) * 2 * HH, stream);
  k_edge_mlp2<0><<<mblk, 256, 0, stream>>>(hb, cei, Wmc, bcp1, s_sum, s_sq,
                                           nullptr, nullptr, nullptr, nullptr, nullptr);
  k_bn_finalize<<<1, 128, 0, stream>>>(s_sum, s_sq, gcp, becp, s_scale, s_shift, 1.0f / EE);
  k_edge_mlp2<1><<<mblk, 256, 0, stream>>>(hb, cei, Wmc, bcp1, nullptr, nullptr,
                                           s_scale, s_shift, Wcp2, bcp2, out + (size_t)2 * EE);

  k_edge_types<<<(2 * EE + 255) / 256, 256, 0, stream>>>(out);
}

// Round 4
// 774.233 us; speedup vs baseline: 4.5114x; 1.3983x over previous
//
#include <hip/hip_runtime.h>
#include <hip/hip_bf16.h>

#define NN 50000
#define EE 250000
#define HH 128
#define EPS_ 1e-5f
#define SCB 196  // scan segments per relation: ceil(NN/256)

typedef __attribute__((ext_vector_type(8))) short bf16x8;
typedef __attribute__((ext_vector_type(4))) float f32x4;

__device__ __forceinline__ float bf2f(ushort u) {
  union { unsigned int i; float f; } x; x.i = ((unsigned int)u) << 16; return x.f;
}
__device__ __forceinline__ ushort f2bf(float f) {
  union { float f; unsigned int i; } x; x.f = f;
  unsigned int r = (x.i + 0x7fffu + ((x.i >> 16) & 1u)) >> 16;  // RNE, finite inputs
  return (ushort)r;
}

// ---------------- degree / CSR build ----------------
__global__ void k_count(const int* __restrict__ bei, const int* __restrict__ cei,
                        int* __restrict__ cntb, int* __restrict__ cntc) {
  int i = blockIdx.x * blockDim.x + threadIdx.x;
  if (i < EE) atomicAdd(&cntb[bei[EE + i]], 1);
  else if (i < 2 * EE) atomicAdd(&cntc[cei[EE + (i - EE)]], 1);
}

__global__ void k_dinv(const int* __restrict__ cnt, float* __restrict__ dinv) {
  int i = blockIdx.x * blockDim.x + threadIdx.x;  // 2N: [cntb|cntc] -> [dinvb|dinvc]
  if (i < 2 * NN) dinv[i] = rsqrtf((float)cnt[i] + 1.0f);
}

// ---- parallel 2-level exclusive scan over cnt[2N] -> off[2N], cur[2N] ----
__global__ void k_scan_part(const int* __restrict__ cnt, int* __restrict__ part) {
  // grid 2*SCB x 256
  int rel = blockIdx.x / SCB, b = blockIdx.x % SCB;
  int n = b * 256 + threadIdx.x;
  int v = (n < NN) ? cnt[rel * NN + n] : 0;
#pragma unroll
  for (int m = 32; m >= 1; m >>= 1) v += __shfl_xor(v, m, 64);
  __shared__ int red[4];
  if ((threadIdx.x & 63) == 0) red[threadIdx.x >> 6] = v;
  __syncthreads();
  if (threadIdx.x == 0) part[rel * SCB + b] = red[0] + red[1] + red[2] + red[3];
}

__global__ void k_scan_base(int* __restrict__ part) {
  // 1 block, 256 threads: in-place exclusive scan of each relation's SCB partials
  __shared__ int s[256];
  int t = threadIdx.x;
  for (int rel = 0; rel < 2; ++rel) {
    int v = (t < SCB) ? part[rel * SCB + t] : 0;
    s[t] = v;
    __syncthreads();
    for (int ofs = 1; ofs < 256; ofs <<= 1) {
      int x = (t >= ofs) ? s[t - ofs] : 0;
      __syncthreads();
      s[t] += x;
      __syncthreads();
    }
    if (t < SCB) part[rel * SCB + t] = s[t] - v;  // exclusive
    __syncthreads();
  }
}

__global__ void k_scan_off(const int* __restrict__ cnt, const int* __restrict__ part,
                           int* __restrict__ off, int* __restrict__ cur) {
  int rel = blockIdx.x / SCB, b = blockIdx.x % SCB;
  int t = threadIdx.x;
  int n = b * 256 + t;
  int v = (n < NN) ? cnt[rel * NN + n] : 0;
  __shared__ int s[256];
  s[t] = v;
  __syncthreads();
  for (int ofs = 1; ofs < 256; ofs <<= 1) {
    int x = (t >= ofs) ? s[t - ofs] : 0;
    __syncthreads();
    s[t] += x;
    __syncthreads();
  }
  if (n < NN) {
    int o = part[rel * SCB + b] + s[t] - v;
    off[rel * NN + n] = o;
    cur[rel * NN + n] = o;
  }
}

__global__ void k_fill(const int* __restrict__ bei, const int* __restrict__ cei,
                       int* __restrict__ curb, int* __restrict__ listb,
                       int* __restrict__ curc, int* __restrict__ listc) {
  int i = blockIdx.x * blockDim.x + threadIdx.x;
  if (i < EE) {
    int dst = bei[EE + i];
    int p = atomicAdd(&curb[dst], 1);
    listb[p] = bei[i];
  } else if (i < 2 * EE) {
    int e = i - EE;
    int dst = cei[EE + e];
    int p = atomicAdd(&curc[dst], 1);
    listc[p] = cei[e];
  }
}

// ---------------- encoder: relu(x@W_enc+b) -> bf16, accumulate BN stats ----------------
__global__ void k_encoder_bf(const float* __restrict__ x, const float* __restrict__ W,
                             const float* __restrict__ b, ushort* __restrict__ hb,
                             float* __restrict__ sum, float* __restrict__ sumsq) {
  int t = threadIdx.x;
  int c = t & 127, r = t >> 7;
  int n0 = blockIdx.x * 64;
  float w0 = W[c], w1 = W[HH + c], w2 = W[2 * HH + c], bb = b[c];
  float ls = 0.f, lss = 0.f;
  for (int rr = r; rr < 64; rr += 2) {
    int n = n0 + rr;
    if (n < NN) {
      float v = fmaxf(x[n * 3] * w0 + x[n * 3 + 1] * w1 + x[n * 3 + 2] * w2 + bb, 0.f);
      ushort u = f2bf(v);
      hb[(size_t)n * HH + c] = u;
      float vr = bf2f(u);          // stats on the rounded value (self-consistent BN)
      ls += vr; lss += vr * vr;
    }
  }
  __shared__ float red[2][HH];
  red[r][c] = ls; __syncthreads();
  if (r == 0) atomicAdd(&sum[c], red[0][c] + red[1][c]);
  __syncthreads();
  red[r][c] = lss; __syncthreads();
  if (r == 0) atomicAdd(&sumsq[c], red[0][c] + red[1][c]);
}

__global__ void k_bn_finalize(const float* __restrict__ sum, const float* __restrict__ sumsq,
                              const float* __restrict__ g, const float* __restrict__ be,
                              float* __restrict__ scale, float* __restrict__ shift, float invn) {
  int c = threadIdx.x;
  float m = sum[c] * invn;
  float v = fmaxf(sumsq[c] * invn - m * m, 0.f);
  float s = g[c] * rsqrtf(v + EPS_);
  scale[c] = s;
  shift[c] = be[c] - m * s;
}

// merged 2-relation finalize; st layout: [sum0,sq0,sum1,sq1,scale0,shift0,scale1,shift1]
__global__ void k_bn_finalize2(float* __restrict__ st, const float* __restrict__ g0,
                               const float* __restrict__ be0, const float* __restrict__ g1,
                               const float* __restrict__ be1, float invn) {
  int t = threadIdx.x;  // 256
  int rel = t >> 7, c = t & 127;
  const float* sum = st + rel * 2 * HH;
  const float* sq  = sum + HH;
  float* scale = st + 4 * HH + rel * 2 * HH;
  float* shift = scale + HH;
  const float* g = rel ? g1 : g0;
  const float* be = rel ? be1 : be0;
  float m = sum[c] * invn;
  float v = fmaxf(sq[c] * invn - m * m, 0.f);
  float s = g[c] * rsqrtf(v + EPS_);
  scale[c] = s;
  shift[c] = be[c] - m * s;
}

__global__ void k_bn_apply_bf(ushort* __restrict__ hb, const float* __restrict__ scale,
                              const float* __restrict__ shift) {
  int i = blockIdx.x * 256 + threadIdx.x;  // i over N*H/4
  if (i * 4 < NN * HH) {
    int base = i * 4, c0 = base & 127;
    ushort4 u = *(ushort4*)&hb[base];
    u.x = f2bf(bf2f(u.x) * scale[c0] + shift[c0]);
    u.y = f2bf(bf2f(u.y) * scale[c0 + 1] + shift[c0 + 1]);
    u.z = f2bf(bf2f(u.z) * scale[c0 + 2] + shift[c0 + 2]);
    u.w = f2bf(bf2f(u.w) * scale[c0 + 3] + shift[c0 + 3]);
    *(ushort4*)&hb[base] = u;
  }
}

// ---------------- weight transposes to bf16 ----------------
__global__ void k_wt128_all(const float* __restrict__ s0, const float* __restrict__ s1,
                            const float* __restrict__ s2, const float* __restrict__ s3,
                            ushort* __restrict__ d0, ushort* __restrict__ d1,
                            ushort* __restrict__ d2, ushort* __restrict__ d3) {
  int i = blockIdx.x * 256 + threadIdx.x;
  if (i < 4 * 128 * 128) {
    int sel = i >> 14, loc = i & 16383;
    int k = loc >> 7, c = loc & 127;
    const float* s = sel == 0 ? s0 : sel == 1 ? s1 : sel == 2 ? s2 : s3;
    ushort* d = sel == 0 ? d0 : sel == 1 ? d1 : sel == 2 ? d2 : d3;
    d[c * 128 + k] = f2bf(s[loc]);
  }
}

__global__ void k_wt256_all(const float* __restrict__ s0, const float* __restrict__ s1,
                            ushort* __restrict__ d0, ushort* __restrict__ d1) {
  int i = blockIdx.x * 256 + threadIdx.x;
  if (i < 2 * 256 * 128) {
    int sel = i >> 15, loc = i & 32767;
    int k = loc >> 7, c = loc & 127;
    const float* s = sel ? s1 : s0;
    ushort* d = sel ? d1 : d0;
    d[c * 256 + k] = f2bf(s[loc]);
  }
}

// ---------------- bf16 GEMM pair: Y{0,1}[N,128] = X[N,128] @ W{0,1} ----------------
__global__ __launch_bounds__(256) void k_gemm_bf2(const ushort* __restrict__ X,
                                                  const ushort* __restrict__ Wt0,
                                                  ushort* __restrict__ Y0,
                                                  const ushort* __restrict__ Wt1,
                                                  ushort* __restrict__ Y1) {
  const int nb = gridDim.x >> 1;
  const int rel = blockIdx.x >= nb;
  const int blk = rel ? blockIdx.x - nb : blockIdx.x;
  const ushort* Wt = rel ? Wt1 : Wt0;
  ushort* Y = rel ? Y1 : Y0;
  const int t = threadIdx.x;
  const int l = t & 63, wid = t >> 6;
  const int wm = wid >> 1, wn = wid & 1;
  const int lr = l & 15, lg = l >> 4;
  const int n0 = blk * 64;
  f32x4 acc[2][4];
#pragma unroll
  for (int mf = 0; mf < 2; ++mf)
#pragma unroll
    for (int nf = 0; nf < 4; ++nf) acc[mf][nf] = (f32x4){0.f, 0.f, 0.f, 0.f};
  int r0 = n0 + wm * 32 + lr;
  int rA = min(r0, NN - 1), rB = min(r0 + 16, NN - 1);
  const ushort* xa = X + (size_t)rA * HH + lg * 8;
  const ushort* xb = X + (size_t)rB * HH + lg * 8;
#pragma unroll
  for (int ks = 0; ks < 4; ++ks) {
    bf16x8 a0 = *(const bf16x8*)(xa + ks * 32);
    bf16x8 a1 = *(const bf16x8*)(xb + ks * 32);
#pragma unroll
    for (int nf = 0; nf < 4; ++nf) {
      int col = wn * 64 + nf * 16 + lr;
      bf16x8 b = *(const bf16x8*)(Wt + col * 128 + ks * 32 + lg * 8);
      acc[0][nf] = __builtin_amdgcn_mfma_f32_16x16x32_bf16(a0, b, acc[0][nf], 0, 0, 0);
      acc[1][nf] = __builtin_amdgcn_mfma_f32_16x16x32_bf16(a1, b, acc[1][nf], 0, 0, 0);
    }
  }
#pragma unroll
  for (int mf = 0; mf < 2; ++mf)
#pragma unroll
    for (int nf = 0; nf < 4; ++nf) {
      int col = wn * 64 + nf * 16 + lr;
#pragma unroll
      for (int j = 0; j < 4; ++j) {
        int row = n0 + wm * 32 + mf * 16 + lg * 4 + j;
        if (row < NN) Y[(size_t)row * HH + col] = f2bf(acc[mf][nf][j]);
      }
    }
}

// ---------------- fused aggregation: bias+self+both relations (+relu) -> bf16 ----------------
template <int RELU>
__global__ void k_agg(const ushort* __restrict__ xwb, const ushort* __restrict__ xwc,
                      const float* __restrict__ dinvb, const float* __restrict__ dinvc,
                      const int* __restrict__ offb, const int* __restrict__ cntb,
                      const int* __restrict__ listb,
                      const int* __restrict__ offc, const int* __restrict__ cntc,
                      const int* __restrict__ listc,
                      const float* __restrict__ bb, const float* __restrict__ bc,
                      ushort* __restrict__ out) {
  int t = threadIdx.x;
  int n = blockIdx.x * 2 + (t >> 7);
  int c = t & 127;
  if (n >= NN) return;
  float dnb = dinvb[n], dnc = dinvc[n];
  float acc = bb[c] + bc[c] + dnb * dnb * bf2f(xwb[(size_t)n * HH + c])
                            + dnc * dnc * bf2f(xwc[(size_t)n * HH + c]);
  int o = offb[n], e = o + cntb[n];
  float s = 0.f;
  for (; o < e; ++o) { int src = listb[o]; s += dinvb[src] * bf2f(xwb[(size_t)src * HH + c]); }
  acc += dnb * s;
  o = offc[n]; e = o + cntc[n];
  s = 0.f;
  for (; o < e; ++o) { int src = listc[o]; s += dinvc[src] * bf2f(xwc[(size_t)src * HH + c]); }
  acc += dnc * s;
  if (RELU) acc = fmaxf(acc, 0.f);
  out[(size_t)n * HH + c] = f2bf(acc);
}

// ---------------- edge MLP (merged 2-relation): no-LDS direct-gather MFMA ----------------
// t = relu(concat(h2[s],h2[d]) @ W1 + b1)  [E x 128], K=256
// PASS2=0: BN stats into st[rel].  PASS2=1: recompute, BN-apply, out = t_hat@W2 + b2.
template <int PASS2>
__global__ __launch_bounds__(256) void k_edge_mlp3(
    const ushort* __restrict__ h2b,
    const int* __restrict__ ei0, const ushort* __restrict__ Wt0, const float* __restrict__ b1_0,
    const int* __restrict__ ei1, const ushort* __restrict__ Wt1, const float* __restrict__ b1_1,
    float* __restrict__ st,
    const float* __restrict__ W2_0, const float* __restrict__ b2_0,
    const float* __restrict__ W2_1, const float* __restrict__ b2_1,
    float* __restrict__ out) {
  const int nb = gridDim.x >> 1;
  const int rel = blockIdx.x >= nb;
  const int blk = rel ? blockIdx.x - nb : blockIdx.x;
  const int* ei = rel ? ei1 : ei0;
  const ushort* W1t = rel ? Wt1 : Wt0;
  const float* b1 = rel ? b1_1 : b1_0;

  __shared__ float redA[HH];
  __shared__ float redB[HH];
  const int t = threadIdx.x;
  const int l = t & 63, wid = t >> 6;
  const int wm = wid >> 1, wn = wid & 1;
  const int lr = l & 15, lg = l >> 4;
  const int e0 = blk * 64;
  if (!PASS2) {
    if (t < HH) { redA[t] = 0.f; redB[t] = 0.f; }
  } else {
    if (t < HH) redA[t] = 0.f;  // reused as red2[64][2]
  }
  __syncthreads();

  int r0 = e0 + wm * 32 + lr;
  int rA = min(r0, EE - 1), rB = min(r0 + 16, EE - 1);
  int sA = ei[rA], dA = ei[EE + rA];
  int sB = ei[rB], dB = ei[EE + rB];

  f32x4 acc[2][4];
#pragma unroll
  for (int mf = 0; mf < 2; ++mf)
#pragma unroll
    for (int nf = 0; nf < 4; ++nf) acc[mf][nf] = (f32x4){0.f, 0.f, 0.f, 0.f};

#pragma unroll
  for (int ks = 0; ks < 8; ++ks) {
    int rowA = (ks < 4) ? sA : dA;
    int rowB = (ks < 4) ? sB : dB;
    int ko = (ks & 3) * 32 + lg * 8;
    bf16x8 a0 = *(const bf16x8*)(h2b + (size_t)rowA * HH + ko);
    bf16x8 a1 = *(const bf16x8*)(h2b + (size_t)rowB * HH + ko);
#pragma unroll
    for (int nf = 0; nf < 4; ++nf) {
      int col = wn * 64 + nf * 16 + lr;
      bf16x8 b = *(const bf16x8*)(W1t + col * 256 + ks * 32 + lg * 8);
      acc[0][nf] = __builtin_amdgcn_mfma_f32_16x16x32_bf16(a0, b, acc[0][nf], 0, 0, 0);
      acc[1][nf] = __builtin_amdgcn_mfma_f32_16x16x32_bf16(a1, b, acc[1][nf], 0, 0, 0);
    }
  }

  if (!PASS2) {
    float* gsum = st + rel * 2 * HH;
    float* gsq  = gsum + HH;
#pragma unroll
    for (int nf = 0; nf < 4; ++nf) {
      int col = wn * 64 + nf * 16 + lr;
      float b1c = b1[col];
      float s = 0.f, q = 0.f;
#pragma unroll
      for (int mf = 0; mf < 2; ++mf)
#pragma unroll
        for (int j = 0; j < 4; ++j) {
          int row = e0 + wm * 32 + mf * 16 + lg * 4 + j;
          if (row < EE) {
            float v = fmaxf(acc[mf][nf][j] + b1c, 0.f);
            s += v; q += v * v;
          }
        }
      atomicAdd(&redA[col], s);
      atomicAdd(&redB[col], q);
    }
    __syncthreads();
    if (t < HH) {
      atomicAdd(&gsum[t], redA[t]);
      atomicAdd(&gsq[t], redB[t]);
    }
  } else {
    const float* scale = st + 4 * HH + rel * 2 * HH;
    const float* shift = scale + HH;
    const float* W2 = rel ? W2_1 : W2_0;
    const float* b2 = rel ? b2_1 : b2_0;
    float* o = out + (size_t)rel * 2 * EE;
    float p0[2][4], p1[2][4];
#pragma unroll
    for (int mf = 0; mf < 2; ++mf)
#pragma unroll
      for (int j = 0; j < 4; ++j) { p0[mf][j] = 0.f; p1[mf][j] = 0.f; }
#pragma unroll
    for (int nf = 0; nf < 4; ++nf) {
      int col = wn * 64 + nf * 16 + lr;
      float b1c = b1[col], sc = scale[col], sh = shift[col];
      float w20 = W2[col * 2], w21 = W2[col * 2 + 1];
#pragma unroll
      for (int mf = 0; mf < 2; ++mf)
#pragma unroll
        for (int j = 0; j < 4; ++j) {
          float v = fmaxf(acc[mf][nf][j] + b1c, 0.f) * sc + sh;
          p0[mf][j] += v * w20;
          p1[mf][j] += v * w21;
        }
    }
#pragma unroll
    for (int m = 8; m >= 1; m >>= 1) {
#pragma unroll
      for (int mf = 0; mf < 2; ++mf)
#pragma unroll
        for (int j = 0; j < 4; ++j) {
          p0[mf][j] += __shfl_xor(p0[mf][j], m, 64);
          p1[mf][j] += __shfl_xor(p1[mf][j], m, 64);
        }
    }
    float* red2 = redA;  // [64][2]
    if (lr == 0) {
#pragma unroll
      for (int mf = 0; mf < 2; ++mf)
#pragma unroll
        for (int j = 0; j < 4; ++j) {
          int row = wm * 32 + mf * 16 + lg * 4 + j;
          atomicAdd(&red2[row * 2 + 0], p0[mf][j]);
          atomicAdd(&red2[row * 2 + 1], p1[mf][j]);
        }
    }
    __syncthreads();
    if (t < 128) {
      int row = t >> 1, j = t & 1;
      int eg = e0 + row;
      if (eg < EE) o[(size_t)eg * 2 + j] = red2[t] + b2[j];
    }
  }
}

// ---------------- edge types ----------------
__global__ void k_edge_types(float* __restrict__ out) {
  int i = blockIdx.x * 256 + threadIdx.x;
  if (i < 2 * EE) out[(size_t)2 * EE * 2 + i] = (i < EE) ? 0.0f : 1.0f;
}

extern "C" void kernel_launch(void* const* d_in, const int* in_sizes, int n_in,
                              void* d_out, int out_size, void* d_ws, size_t ws_size,
                              hipStream_t stream) {
  const float* x      = (const float*)d_in[0];
  const int*   bei    = (const int*)d_in[1];
  const int*   cei    = (const int*)d_in[2];
  const float* W_enc  = (const float*)d_in[3];
  const float* b_enc  = (const float*)d_in[4];
  const float* g_enc  = (const float*)d_in[5];
  const float* be_enc = (const float*)d_in[6];
  const float* W1b = (const float*)d_in[7];  const float* b1b = (const float*)d_in[8];
  const float* W1c = (const float*)d_in[9];  const float* b1c = (const float*)d_in[10];
  const float* W2b = (const float*)d_in[11]; const float* b2b = (const float*)d_in[12];
  const float* W2c = (const float*)d_in[13]; const float* b2c = (const float*)d_in[14];
  const float* Wbp1 = (const float*)d_in[15]; const float* bbp1 = (const float*)d_in[16];
  const float* gbp  = (const float*)d_in[17]; const float* bebp = (const float*)d_in[18];
  const float* Wbp2 = (const float*)d_in[19]; const float* bbp2 = (const float*)d_in[20];
  const float* Wcp1 = (const float*)d_in[21]; const float* bcp1 = (const float*)d_in[22];
  const float* gcp  = (const float*)d_in[23]; const float* becp = (const float*)d_in[24];
  const float* Wcp2 = (const float*)d_in[25]; const float* bcp2 = (const float*)d_in[26];
  float* out = (float*)d_out;

  // ---- workspace layout (~55 MB) ----
  ushort* hb   = (ushort*)d_ws;                 // h (bf16); later h2  [N*H]
  ushort* h1b  = hb + (size_t)NN * HH;          // h1 bf16
  ushort* xwb  = h1b + (size_t)NN * HH;         // per-relation x@W bf16
  ushort* xwc  = xwb + (size_t)NN * HH;
  ushort* Wt1b = xwc + (size_t)NN * HH;         // 128x128 transposed weights (bf16)
  ushort* Wt1c = Wt1b + 128 * 128;
  ushort* Wt2b = Wt1c + 128 * 128;
  ushort* Wt2c = Wt2b + 128 * 128;
  ushort* Wmb  = Wt2c + 128 * 128;              // MLP W1^T [128][256]
  ushort* Wmc  = Wmb + 256 * 128;
  float* dinv  = (float*)(Wmc + 256 * 128);     // dinvb[N], dinvc[N]
  float* dinvb = dinv, *dinvc = dinv + NN;
  float* st    = dinvc + NN;                    // [sum0,sq0,sum1,sq1,scale0,shift0,scale1,shift1]
  int* cnt  = (int*)(st + 8 * HH);              // cntb[N], cntc[N]
  int* cntb = cnt, *cntc = cnt + NN;
  int* offb = cntc + NN; int* offc = offb + NN;
  int* curb = offc + NN; int* curc = curb + NN;
  int* part = curc + NN;                        // scan partials [2*SCB]
  int* listb = part + 2 * SCB; int* listc = listb + EE;

  // ---- degrees + CSR (parallel scan) ----
  hipMemsetAsync(cnt, 0, sizeof(int) * 2 * NN, stream);
  hipMemsetAsync(st, 0, sizeof(float) * 2 * HH, stream);
  k_count<<<(2 * EE + 255) / 256, 256, 0, stream>>>(bei, cei, cntb, cntc);
  k_dinv<<<(2 * NN + 255) / 256, 256, 0, stream>>>(cnt, dinv);
  k_scan_part<<<2 * SCB, 256, 0, stream>>>(cnt, part);
  k_scan_base<<<1, 256, 0, stream>>>(part);
  k_scan_off<<<2 * SCB, 256, 0, stream>>>(cnt, part, offb, curb);
  k_fill<<<(2 * EE + 255) / 256, 256, 0, stream>>>(bei, cei, curb, listb, curc, listc);

  // ---- encoder + BN -> hb (bf16) ----
  k_encoder_bf<<<(NN + 63) / 64, 256, 0, stream>>>(x, W_enc, b_enc, hb, st, st + HH);
  k_bn_finalize<<<1, 128, 0, stream>>>(st, st + HH, g_enc, be_enc, st + 4 * HH, st + 5 * HH,
                                       1.0f / NN);
  k_bn_apply_bf<<<(NN * HH / 4 + 255) / 256, 256, 0, stream>>>(hb, st + 4 * HH, st + 5 * HH);

  // ---- weight transposes ----
  k_wt128_all<<<(4 * 16384 + 255) / 256, 256, 0, stream>>>(W1b, W1c, W2b, W2c,
                                                           Wt1b, Wt1c, Wt2b, Wt2c);
  k_wt256_all<<<(2 * 32768 + 255) / 256, 256, 0, stream>>>(Wbp1, Wcp1, Wmb, Wmc);

  int gblk = (NN + 63) / 64;
  int ablk = (NN + 1) / 2;
  // ---- GCN layer 1: h1 = relu(agg_b + agg_c) ----
  k_gemm_bf2<<<2 * gblk, 256, 0, stream>>>(hb, Wt1b, xwb, Wt1c, xwc);
  k_agg<1><<<ablk, 256, 0, stream>>>(xwb, xwc, dinvb, dinvc, offb, cntb, listb,
                                     offc, cntc, listc, b1b, b1c, h1b);
  // ---- GCN layer 2: h2 (into hb slot) ----
  k_gemm_bf2<<<2 * gblk, 256, 0, stream>>>(h1b, Wt2b, xwb, Wt2c, xwc);
  k_agg<0><<<ablk, 256, 0, stream>>>(xwb, xwc, dinvb, dinvc, offb, cntb, listb,
                                     offc, cntc, listc, b2b, b2c, hb);

  // ---- edge predictors (both relations per launch) ----
  int mblk = (EE + 63) / 64;
  hipMemsetAsync(st, 0, sizeof(float) * 4 * HH, stream);
  k_edge_mlp3<0><<<2 * mblk, 256, 0, stream>>>(hb, bei, Wmb, bbp1, cei, Wmc, bcp1, st,
                                               nullptr, nullptr, nullptr, nullptr, nullptr);
  k_bn_finalize2<<<1, 256, 0, stream>>>(st, gbp, bebp, gcp, becp, 1.0f / EE);
  k_edge_mlp3<1><<<2 * mblk, 256, 0, stream>>>(hb, bei, Wmb, bbp1, cei, Wmc, bcp1, st,
                                               Wbp2, bbp2, Wcp2, bcp2, out);

  k_edge_types<<<(2 * EE + 255) / 256, 256, 0, stream>>>(out);
}

// Round 5
// 749.022 us; speedup vs baseline: 4.6632x; 1.0337x over previous
//
#include <hip/hip_runtime.h>
#include <hip/hip_bf16.h>

#define NN 50000
#define EE 250000
#define HH 128
#define EPS_ 1e-5f
#define SCB 196  // scan segments per relation: ceil(NN/256)

typedef __attribute__((ext_vector_type(8))) short bf16x8;
typedef __attribute__((ext_vector_type(4))) float f32x4;

__device__ __forceinline__ float bf2f(ushort u) {
  union { unsigned int i; float f; } x; x.i = ((unsigned int)u) << 16; return x.f;
}
__device__ __forceinline__ ushort f2bf(float f) {
  union { float f; unsigned int i; } x; x.f = f;
  unsigned int r = (x.i + 0x7fffu + ((x.i >> 16) & 1u)) >> 16;  // RNE, finite inputs
  return (ushort)r;
}

// ---------------- degree / CSR build ----------------
__global__ void k_count(const int* __restrict__ bei, const int* __restrict__ cei,
                        int* __restrict__ cntb, int* __restrict__ cntc) {
  int i = blockIdx.x * blockDim.x + threadIdx.x;
  if (i < EE) atomicAdd(&cntb[bei[EE + i]], 1);
  else if (i < 2 * EE) atomicAdd(&cntc[cei[EE + (i - EE)]], 1);
}

__global__ void k_dinv(const int* __restrict__ cnt, float* __restrict__ dinv) {
  int i = blockIdx.x * blockDim.x + threadIdx.x;  // 2N: [cntb|cntc] -> [dinvb|dinvc]
  if (i < 2 * NN) dinv[i] = rsqrtf((float)cnt[i] + 1.0f);
}

// ---- parallel 2-level exclusive scan over cnt[2N] -> off[2N], cur[2N] ----
__global__ void k_scan_part(const int* __restrict__ cnt, int* __restrict__ part) {
  int rel = blockIdx.x / SCB, b = blockIdx.x % SCB;
  int n = b * 256 + threadIdx.x;
  int v = (n < NN) ? cnt[rel * NN + n] : 0;
#pragma unroll
  for (int m = 32; m >= 1; m >>= 1) v += __shfl_xor(v, m, 64);
  __shared__ int red[4];
  if ((threadIdx.x & 63) == 0) red[threadIdx.x >> 6] = v;
  __syncthreads();
  if (threadIdx.x == 0) part[rel * SCB + b] = red[0] + red[1] + red[2] + red[3];
}

__global__ void k_scan_base(int* __restrict__ part) {
  __shared__ int s[256];
  int t = threadIdx.x;
  for (int rel = 0; rel < 2; ++rel) {
    int v = (t < SCB) ? part[rel * SCB + t] : 0;
    s[t] = v;
    __syncthreads();
    for (int ofs = 1; ofs < 256; ofs <<= 1) {
      int x = (t >= ofs) ? s[t - ofs] : 0;
      __syncthreads();
      s[t] += x;
      __syncthreads();
    }
    if (t < SCB) part[rel * SCB + t] = s[t] - v;  // exclusive
    __syncthreads();
  }
}

__global__ void k_scan_off(const int* __restrict__ cnt, const int* __restrict__ part,
                           int* __restrict__ off, int* __restrict__ cur) {
  int rel = blockIdx.x / SCB, b = blockIdx.x % SCB;
  int t = threadIdx.x;
  int n = b * 256 + t;
  int v = (n < NN) ? cnt[rel * NN + n] : 0;
  __shared__ int s[256];
  s[t] = v;
  __syncthreads();
  for (int ofs = 1; ofs < 256; ofs <<= 1) {
    int x = (t >= ofs) ? s[t - ofs] : 0;
    __syncthreads();
    s[t] += x;
    __syncthreads();
  }
  if (n < NN) {
    int o = part[rel * SCB + b] + s[t] - v;
    off[rel * NN + n] = o;
    cur[rel * NN + n] = o;
  }
}

__global__ void k_fill(const int* __restrict__ bei, const int* __restrict__ cei,
                       int* __restrict__ curb, int* __restrict__ listb,
                       int* __restrict__ curc, int* __restrict__ listc) {
  int i = blockIdx.x * blockDim.x + threadIdx.x;
  if (i < EE) {
    int dst = bei[EE + i];
    int p = atomicAdd(&curb[dst], 1);
    listb[p] = bei[i];
  } else if (i < 2 * EE) {
    int e = i - EE;
    int dst = cei[EE + e];
    int p = atomicAdd(&curc[dst], 1);
    listc[p] = cei[e];
  }
}

// ---------------- encoder: relu(x@W_enc+b) -> bf16, accumulate BN stats ----------------
__global__ void k_encoder_bf(const float* __restrict__ x, const float* __restrict__ W,
                             const float* __restrict__ b, ushort* __restrict__ hb,
                             float* __restrict__ sum, float* __restrict__ sumsq) {
  int t = threadIdx.x;
  int c = t & 127, r = t >> 7;
  int n0 = blockIdx.x * 64;
  float w0 = W[c], w1 = W[HH + c], w2 = W[2 * HH + c], bb = b[c];
  float ls = 0.f, lss = 0.f;
  for (int rr = r; rr < 64; rr += 2) {
    int n = n0 + rr;
    if (n < NN) {
      float v = fmaxf(x[n * 3] * w0 + x[n * 3 + 1] * w1 + x[n * 3 + 2] * w2 + bb, 0.f);
      ushort u = f2bf(v);
      hb[(size_t)n * HH + c] = u;
      float vr = bf2f(u);          // stats on the rounded value (self-consistent BN)
      ls += vr; lss += vr * vr;
    }
  }
  __shared__ float red[2][HH];
  red[r][c] = ls; __syncthreads();
  if (r == 0) atomicAdd(&sum[c], red[0][c] + red[1][c]);
  __syncthreads();
  red[r][c] = lss; __syncthreads();
  if (r == 0) atomicAdd(&sumsq[c], red[0][c] + red[1][c]);
}

__global__ void k_bn_finalize(const float* __restrict__ sum, const float* __restrict__ sumsq,
                              const float* __restrict__ g, const float* __restrict__ be,
                              float* __restrict__ scale, float* __restrict__ shift, float invn) {
  int c = threadIdx.x;
  float m = sum[c] * invn;
  float v = fmaxf(sumsq[c] * invn - m * m, 0.f);
  float s = g[c] * rsqrtf(v + EPS_);
  scale[c] = s;
  shift[c] = be[c] - m * s;
}

// merged 2-relation finalize; st layout: [sum0,sq0,sum1,sq1,scale0,shift0,scale1,shift1]
__global__ void k_bn_finalize2(float* __restrict__ st, const float* __restrict__ g0,
                               const float* __restrict__ be0, const float* __restrict__ g1,
                               const float* __restrict__ be1, float invn) {
  int t = threadIdx.x;  // 256
  int rel = t >> 7, c = t & 127;
  const float* sum = st + rel * 2 * HH;
  const float* sq  = sum + HH;
  float* scale = st + 4 * HH + rel * 2 * HH;
  float* shift = scale + HH;
  const float* g = rel ? g1 : g0;
  const float* be = rel ? be1 : be0;
  float m = sum[c] * invn;
  float v = fmaxf(sq[c] * invn - m * m, 0.f);
  float s = g[c] * rsqrtf(v + EPS_);
  scale[c] = s;
  shift[c] = be[c] - m * s;
}

__global__ void k_bn_apply_bf(ushort* __restrict__ hb, const float* __restrict__ scale,
                              const float* __restrict__ shift) {
  int i = blockIdx.x * 256 + threadIdx.x;  // i over N*H/4
  if (i * 4 < NN * HH) {
    int base = i * 4, c0 = base & 127;
    ushort4 u = *(ushort4*)&hb[base];
    u.x = f2bf(bf2f(u.x) * scale[c0] + shift[c0]);
    u.y = f2bf(bf2f(u.y) * scale[c0 + 1] + shift[c0 + 1]);
    u.z = f2bf(bf2f(u.z) * scale[c0 + 2] + shift[c0 + 2]);
    u.w = f2bf(bf2f(u.w) * scale[c0 + 3] + shift[c0 + 3]);
    *(ushort4*)&hb[base] = u;
  }
}

// ---------------- weight transposes to bf16 ----------------
__global__ void k_wt128_all(const float* __restrict__ s0, const float* __restrict__ s1,
                            const float* __restrict__ s2, const float* __restrict__ s3,
                            ushort* __restrict__ d0, ushort* __restrict__ d1,
                            ushort* __restrict__ d2, ushort* __restrict__ d3) {
  int i = blockIdx.x * 256 + threadIdx.x;
  if (i < 4 * 128 * 128) {
    int sel = i >> 14, loc = i & 16383;
    int k = loc >> 7, c = loc & 127;
    const float* s = sel == 0 ? s0 : sel == 1 ? s1 : sel == 2 ? s2 : s3;
    ushort* d = sel == 0 ? d0 : sel == 1 ? d1 : sel == 2 ? d2 : d3;
    d[c * 128 + k] = f2bf(s[loc]);
  }
}

__global__ void k_wt256_all(const float* __restrict__ s0, const float* __restrict__ s1,
                            ushort* __restrict__ d0, ushort* __restrict__ d1) {
  int i = blockIdx.x * 256 + threadIdx.x;
  if (i < 2 * 256 * 128) {
    int sel = i >> 15, loc = i & 32767;
    int k = loc >> 7, c = loc & 127;
    const float* s = sel ? s1 : s0;
    ushort* d = sel ? d1 : d0;
    d[c * 256 + k] = f2bf(s[loc]);
  }
}

// ---------------- bf16 GEMM pair: Y{0,1}[N,128] = X[N,128] @ W{0,1} ----------------
__global__ __launch_bounds__(256) void k_gemm_bf2(const ushort* __restrict__ X,
                                                  const ushort* __restrict__ Wt0,
                                                  ushort* __restrict__ Y0,
                                                  const ushort* __restrict__ Wt1,
                                                  ushort* __restrict__ Y1) {
  const int nb = gridDim.x >> 1;
  const int rel = blockIdx.x >= nb;
  const int blk = rel ? blockIdx.x - nb : blockIdx.x;
  const ushort* Wt = rel ? Wt1 : Wt0;
  ushort* Y = rel ? Y1 : Y0;
  const int t = threadIdx.x;
  const int l = t & 63, wid = t >> 6;
  const int wm = wid >> 1, wn = wid & 1;
  const int lr = l & 15, lg = l >> 4;
  const int n0 = blk * 64;
  f32x4 acc[2][4];
#pragma unroll
  for (int mf = 0; mf < 2; ++mf)
#pragma unroll
    for (int nf = 0; nf < 4; ++nf) acc[mf][nf] = (f32x4){0.f, 0.f, 0.f, 0.f};
  int r0 = n0 + wm * 32 + lr;
  int rA = min(r0, NN - 1), rB = min(r0 + 16, NN - 1);
  const ushort* xa = X + (size_t)rA * HH + lg * 8;
  const ushort* xb = X + (size_t)rB * HH + lg * 8;
#pragma unroll
  for (int ks = 0; ks < 4; ++ks) {
    bf16x8 a0 = *(const bf16x8*)(xa + ks * 32);
    bf16x8 a1 = *(const bf16x8*)(xb + ks * 32);
#pragma unroll
    for (int nf = 0; nf < 4; ++nf) {
      int col = wn * 64 + nf * 16 + lr;
      bf16x8 b = *(const bf16x8*)(Wt + col * 128 + ks * 32 + lg * 8);
      acc[0][nf] = __builtin_amdgcn_mfma_f32_16x16x32_bf16(a0, b, acc[0][nf], 0, 0, 0);
      acc[1][nf] = __builtin_amdgcn_mfma_f32_16x16x32_bf16(a1, b, acc[1][nf], 0, 0, 0);
    }
  }
#pragma unroll
  for (int mf = 0; mf < 2; ++mf)
#pragma unroll
    for (int nf = 0; nf < 4; ++nf) {
      int col = wn * 64 + nf * 16 + lr;
#pragma unroll
      for (int j = 0; j < 4; ++j) {
        int row = n0 + wm * 32 + mf * 16 + lg * 4 + j;
        if (row < NN) Y[(size_t)row * HH + col] = f2bf(acc[mf][nf][j]);
      }
    }
}

// ---------------- fused aggregation: bias+self+both relations (+relu) -> bf16 ----------------
template <int RELU>
__global__ void k_agg(const ushort* __restrict__ xwb, const ushort* __restrict__ xwc,
                      const float* __restrict__ dinvb, const float* __restrict__ dinvc,
                      const int* __restrict__ offb, const int* __restrict__ cntb,
                      const int* __restrict__ listb,
                      const int* __restrict__ offc, const int* __restrict__ cntc,
                      const int* __restrict__ listc,
                      const float* __restrict__ bb, const float* __restrict__ bc,
                      ushort* __restrict__ out) {
  int t = threadIdx.x;
  int n = blockIdx.x * 2 + (t >> 7);
  int c = t & 127;
  if (n >= NN) return;
  float dnb = dinvb[n], dnc = dinvc[n];
  float acc = bb[c] + bc[c] + dnb * dnb * bf2f(xwb[(size_t)n * HH + c])
                            + dnc * dnc * bf2f(xwc[(size_t)n * HH + c]);
  int o = offb[n], e = o + cntb[n];
  float s = 0.f;
  for (; o < e; ++o) { int src = listb[o]; s += dinvb[src] * bf2f(xwb[(size_t)src * HH + c]); }
  acc += dnb * s;
  o = offc[n]; e = o + cntc[n];
  s = 0.f;
  for (; o < e; ++o) { int src = listc[o]; s += dinvc[src] * bf2f(xwc[(size_t)src * HH + c]); }
  acc += dnc * s;
  if (RELU) acc = fmaxf(acc, 0.f);
  out[(size_t)n * HH + c] = f2bf(acc);
}

// ---------------- edge MLP v4: ILP-restructured no-LDS direct-gather MFMA ----------------
// Block = 128 edges, 4 waves; each wave owns 32 edges x all 128 cols, K=256.
// A-fragments prefetched 8-at-a-time (src half, then dst half) for memory-level parallelism.
// PASS2=0: BN stats into st[rel].  PASS2=1: recompute, BN-apply, out = t_hat@W2 + b2 (LDS-free).
template <int PASS2>
__global__ __launch_bounds__(256, 3) void k_edge_mlp4(
    const ushort* __restrict__ h2b,
    const int* __restrict__ ei0, const ushort* __restrict__ Wt0, const float* __restrict__ b1_0,
    const int* __restrict__ ei1, const ushort* __restrict__ Wt1, const float* __restrict__ b1_1,
    float* __restrict__ st,
    const float* __restrict__ W2_0, const float* __restrict__ b2_0,
    const float* __restrict__ W2_1, const float* __restrict__ b2_1,
    float* __restrict__ out) {
  const int nb = gridDim.x >> 1;
  const int rel = blockIdx.x >= nb;
  const int blk = rel ? blockIdx.x - nb : blockIdx.x;
  const int* ei = rel ? ei1 : ei0;
  const ushort* W1t = rel ? Wt1 : Wt0;
  const float* b1 = rel ? b1_1 : b1_0;

  const int t = threadIdx.x;
  const int l = t & 63, wid = t >> 6;
  const int lr = l & 15, lg = l >> 4;
  const int e0 = blk * 128 + wid * 32;   // this wave's 32 edges

  __shared__ float redA[HH], redB[HH];
  if (!PASS2) {
    if (t < HH) { redA[t] = 0.f; redB[t] = 0.f; }
    __syncthreads();
  }

  int r0 = min(e0 + lr, EE - 1);
  int r1 = min(e0 + 16 + lr, EE - 1);
  int s0 = ei[r0], d0 = ei[EE + r0];
  int s1 = ei[r1], d1 = ei[EE + r1];

  f32x4 acc[2][8];
#pragma unroll
  for (int mf = 0; mf < 2; ++mf)
#pragma unroll
    for (int nf = 0; nf < 8; ++nf) acc[mf][nf] = (f32x4){0.f, 0.f, 0.f, 0.f};

  // ---- src half: global k 0..127 ----
  {
    bf16x8 a[2][4];
#pragma unroll
    for (int ks = 0; ks < 4; ++ks) {
      a[0][ks] = *(const bf16x8*)(h2b + (size_t)s0 * HH + ks * 32 + lg * 8);
      a[1][ks] = *(const bf16x8*)(h2b + (size_t)s1 * HH + ks * 32 + lg * 8);
    }
#pragma unroll
    for (int ks = 0; ks < 4; ++ks) {
#pragma unroll
      for (int nf = 0; nf < 8; ++nf) {
        bf16x8 b = *(const bf16x8*)(W1t + (nf * 16 + lr) * 256 + ks * 32 + lg * 8);
        acc[0][nf] = __builtin_amdgcn_mfma_f32_16x16x32_bf16(a[0][ks], b, acc[0][nf], 0, 0, 0);
        acc[1][nf] = __builtin_amdgcn_mfma_f32_16x16x32_bf16(a[1][ks], b, acc[1][nf], 0, 0, 0);
      }
    }
  }
  // ---- dst half: global k 128..255 ----
  {
    bf16x8 a[2][4];
#pragma unroll
    for (int ks = 0; ks < 4; ++ks) {
      a[0][ks] = *(const bf16x8*)(h2b + (size_t)d0 * HH + ks * 32 + lg * 8);
      a[1][ks] = *(const bf16x8*)(h2b + (size_t)d1 * HH + ks * 32 + lg * 8);
    }
#pragma unroll
    for (int ks = 0; ks < 4; ++ks) {
#pragma unroll
      for (int nf = 0; nf < 8; ++nf) {
        bf16x8 b = *(const bf16x8*)(W1t + (nf * 16 + lr) * 256 + 128 + ks * 32 + lg * 8);
        acc[0][nf] = __builtin_amdgcn_mfma_f32_16x16x32_bf16(a[0][ks], b, acc[0][nf], 0, 0, 0);
        acc[1][nf] = __builtin_amdgcn_mfma_f32_16x16x32_bf16(a[1][ks], b, acc[1][nf], 0, 0, 0);
      }
    }
  }

  if (!PASS2) {
    float* gsum = st + rel * 2 * HH;
    float* gsq  = gsum + HH;
#pragma unroll
    for (int nf = 0; nf < 8; ++nf) {
      int col = nf * 16 + lr;
      float b1c = b1[col];
      float s = 0.f, q = 0.f;
#pragma unroll
      for (int mf = 0; mf < 2; ++mf)
#pragma unroll
        for (int j = 0; j < 4; ++j) {
          int row = e0 + mf * 16 + lg * 4 + j;
          if (row < EE) {
            float v = fmaxf(acc[mf][nf][j] + b1c, 0.f);
            s += v; q += v * v;
          }
        }
      // reduce across the 4 lg-groups (lanes differing in bits 4,5)
      s += __shfl_xor(s, 16, 64); s += __shfl_xor(s, 32, 64);
      q += __shfl_xor(q, 16, 64); q += __shfl_xor(q, 32, 64);
      if (lg == 0) { atomicAdd(&redA[col], s); atomicAdd(&redB[col], q); }
    }
    __syncthreads();
    if (t < HH) {
      atomicAdd(&gsum[t], redA[t]);
      atomicAdd(&gsq[t], redB[t]);
    }
  } else {
    const float* scale = st + 4 * HH + rel * 2 * HH;
    const float* shift = scale + HH;
    const float* W2 = rel ? W2_1 : W2_0;
    const float* b2 = rel ? b2_1 : b2_0;
    float* o = out + (size_t)rel * 2 * EE;
    float p0[2][4], p1[2][4];
#pragma unroll
    for (int mf = 0; mf < 2; ++mf)
#pragma unroll
      for (int j = 0; j < 4; ++j) { p0[mf][j] = 0.f; p1[mf][j] = 0.f; }
#pragma unroll
    for (int nf = 0; nf < 8; ++nf) {
      int col = nf * 16 + lr;
      float b1c = b1[col], sc = scale[col], sh = shift[col];
      float w20 = W2[col * 2], w21 = W2[col * 2 + 1];
#pragma unroll
      for (int mf = 0; mf < 2; ++mf)
#pragma unroll
        for (int j = 0; j < 4; ++j) {
          float v = fmaxf(acc[mf][nf][j] + b1c, 0.f) * sc + sh;
          p0[mf][j] += v * w20;
          p1[mf][j] += v * w21;
        }
    }
    // reduce across the 16 lr lanes (bits 0..3); each 16-lane group = one lg
#pragma unroll
    for (int m = 8; m >= 1; m >>= 1) {
#pragma unroll
      for (int mf = 0; mf < 2; ++mf)
#pragma unroll
        for (int j = 0; j < 4; ++j) {
          p0[mf][j] += __shfl_xor(p0[mf][j], m, 64);
          p1[mf][j] += __shfl_xor(p1[mf][j], m, 64);
        }
    }
    if (lr == 0) {
      float b20 = b2[0], b21 = b2[1];
#pragma unroll
      for (int mf = 0; mf < 2; ++mf)
#pragma unroll
        for (int j = 0; j < 4; ++j) {
          int row = e0 + mf * 16 + lg * 4 + j;
          if (row < EE) {
            o[(size_t)row * 2 + 0] = p0[mf][j] + b20;
            o[(size_t)row * 2 + 1] = p1[mf][j] + b21;
          }
        }
    }
  }
}

// ---------------- edge types ----------------
__global__ void k_edge_types(float* __restrict__ out) {
  int i = blockIdx.x * 256 + threadIdx.x;
  if (i < 2 * EE) out[(size_t)2 * EE * 2 + i] = (i < EE) ? 0.0f : 1.0f;
}

extern "C" void kernel_launch(void* const* d_in, const int* in_sizes, int n_in,
                              void* d_out, int out_size, void* d_ws, size_t ws_size,
                              hipStream_t stream) {
  const float* x      = (const float*)d_in[0];
  const int*   bei    = (const int*)d_in[1];
  const int*   cei    = (const int*)d_in[2];
  const float* W_enc  = (const float*)d_in[3];
  const float* b_enc  = (const float*)d_in[4];
  const float* g_enc  = (const float*)d_in[5];
  const float* be_enc = (const float*)d_in[6];
  const float* W1b = (const float*)d_in[7];  const float* b1b = (const float*)d_in[8];
  const float* W1c = (const float*)d_in[9];  const float* b1c = (const float*)d_in[10];
  const float* W2b = (const float*)d_in[11]; const float* b2b = (const float*)d_in[12];
  const float* W2c = (const float*)d_in[13]; const float* b2c = (const float*)d_in[14];
  const float* Wbp1 = (const float*)d_in[15]; const float* bbp1 = (const float*)d_in[16];
  const float* gbp  = (const float*)d_in[17]; const float* bebp = (const float*)d_in[18];
  const float* Wbp2 = (const float*)d_in[19]; const float* bbp2 = (const float*)d_in[20];
  const float* Wcp1 = (const float*)d_in[21]; const float* bcp1 = (const float*)d_in[22];
  const float* gcp  = (const float*)d_in[23]; const float* becp = (const float*)d_in[24];
  const float* Wcp2 = (const float*)d_in[25]; const float* bcp2 = (const float*)d_in[26];
  float* out = (float*)d_out;

  // ---- workspace layout (~57 MB) ----
  ushort* hb   = (ushort*)d_ws;                 // h (bf16); later h2  [N*H]
  ushort* h1b  = hb + (size_t)NN * HH;          // h1 bf16
  ushort* xwb  = h1b + (size_t)NN * HH;         // per-relation x@W bf16
  ushort* xwc  = xwb + (size_t)NN * HH;
  ushort* Wt1b = xwc + (size_t)NN * HH;         // 128x128 transposed weights (bf16)
  ushort* Wt1c = Wt1b + 128 * 128;
  ushort* Wt2b = Wt1c + 128 * 128;
  ushort* Wt2c = Wt2b + 128 * 128;
  ushort* Wmb  = Wt2c + 128 * 128;              // MLP W1^T [128][256]
  ushort* Wmc  = Wmb + 256 * 128;
  float* dinv  = (float*)(Wmc + 256 * 128);     // dinvb[N], dinvc[N]
  float* dinvb = dinv, *dinvc = dinv + NN;
  float* st    = dinvc + NN;                    // [sum0,sq0,sum1,sq1,scale0,shift0,scale1,shift1]
  int* cnt  = (int*)(st + 8 * HH);              // cntb[N], cntc[N]
  int* cntb = cnt, *cntc = cnt + NN;
  int* offb = cntc + NN; int* offc = offb + NN;
  int* curb = offc + NN; int* curc = curb + NN;
  int* part = curc + NN;                        // scan partials [2*SCB]
  int* listb = part + 2 * SCB; int* listc = listb + EE;

  // ---- degrees + CSR (parallel scan) ----
  hipMemsetAsync(cnt, 0, sizeof(int) * 2 * NN, stream);
  hipMemsetAsync(st, 0, sizeof(float) * 2 * HH, stream);
  k_count<<<(2 * EE + 255) / 256, 256, 0, stream>>>(bei, cei, cntb, cntc);
  k_dinv<<<(2 * NN + 255) / 256, 256, 0, stream>>>(cnt, dinv);
  k_scan_part<<<2 * SCB, 256, 0, stream>>>(cnt, part);
  k_scan_base<<<1, 256, 0, stream>>>(part);
  k_scan_off<<<2 * SCB, 256, 0, stream>>>(cnt, part, offb, curb);
  k_fill<<<(2 * EE + 255) / 256, 256, 0, stream>>>(bei, cei, curb, listb, curc, listc);

  // ---- encoder + BN -> hb (bf16) ----
  k_encoder_bf<<<(NN + 63) / 64, 256, 0, stream>>>(x, W_enc, b_enc, hb, st, st + HH);
  k_bn_finalize<<<1, 128, 0, stream>>>(st, st + HH, g_enc, be_enc, st + 4 * HH, st + 5 * HH,
                                       1.0f / NN);
  k_bn_apply_bf<<<(NN * HH / 4 + 255) / 256, 256, 0, stream>>>(hb, st + 4 * HH, st + 5 * HH);

  // ---- weight transposes ----
  k_wt128_all<<<(4 * 16384 + 255) / 256, 256, 0, stream>>>(W1b, W1c, W2b, W2c,
                                                           Wt1b, Wt1c, Wt2b, Wt2c);
  k_wt256_all<<<(2 * 32768 + 255) / 256, 256, 0, stream>>>(Wbp1, Wcp1, Wmb, Wmc);

  int gblk = (NN + 63) / 64;
  int ablk = (NN + 1) / 2;
  // ---- GCN layer 1: h1 = relu(agg_b + agg_c) ----
  k_gemm_bf2<<<2 * gblk, 256, 0, stream>>>(hb, Wt1b, xwb, Wt1c, xwc);
  k_agg<1><<<ablk, 256, 0, stream>>>(xwb, xwc, dinvb, dinvc, offb, cntb, listb,
                                     offc, cntc, listc, b1b, b1c, h1b);
  // ---- GCN layer 2: h2 (into hb slot) ----
  k_gemm_bf2<<<2 * gblk, 256, 0, stream>>>(h1b, Wt2b, xwb, Wt2c, xwc);
  k_agg<0><<<ablk, 256, 0, stream>>>(xwb, xwc, dinvb, dinvc, offb, cntb, listb,
                                     offc, cntc, listc, b2b, b2c, hb);

  // ---- edge predictors (both relations per launch) ----
  int mblk = (EE + 127) / 128;
  hipMemsetAsync(st, 0, sizeof(float) * 4 * HH, stream);
  k_edge_mlp4<0><<<2 * mblk, 256, 0, stream>>>(hb, bei, Wmb, bbp1, cei, Wmc, bcp1, st,
                                               nullptr, nullptr, nullptr, nullptr, nullptr);
  k_bn_finalize2<<<1, 256, 0, stream>>>(st, gbp, bebp, gcp, becp, 1.0f / EE);
  k_edge_mlp4<1><<<2 * mblk, 256, 0, stream>>>(hb, bei, Wmb, bbp1, cei, Wmc, bcp1, st,
                                               Wbp2, bbp2, Wcp2, bcp2, out);

  k_edge_types<<<(2 * EE + 255) / 256, 256, 0, stream>>>(out);
}

// Round 6
// 630.111 us; speedup vs baseline: 5.5432x; 1.1887x over previous
//
#include <hip/hip_runtime.h>
#include <hip/hip_bf16.h>

#define NN 50000
#define EE 250000
#define HH 128
#define EPS_ 1e-5f
#define SCB 196  // scan segments per relation: ceil(NN/256)

typedef __attribute__((ext_vector_type(8))) short bf16x8;
typedef __attribute__((ext_vector_type(4))) float f32x4;

__device__ __forceinline__ float bf2f(ushort u) {
  union { unsigned int i; float f; } x; x.i = ((unsigned int)u) << 16; return x.f;
}
__device__ __forceinline__ ushort f2bf(float f) {
  union { float f; unsigned int i; } x; x.f = f;
  unsigned int r = (x.i + 0x7fffu + ((x.i >> 16) & 1u)) >> 16;  // RNE, finite inputs
  return (ushort)r;
}

// ---------------- degree / CSR build ----------------
__global__ void k_count(const int* __restrict__ bei, const int* __restrict__ cei,
                        int* __restrict__ cntb, int* __restrict__ cntc) {
  int i = blockIdx.x * blockDim.x + threadIdx.x;
  if (i < EE) atomicAdd(&cntb[bei[EE + i]], 1);
  else if (i < 2 * EE) atomicAdd(&cntc[cei[EE + (i - EE)]], 1);
}

__global__ void k_dinv(const int* __restrict__ cnt, float* __restrict__ dinv) {
  int i = blockIdx.x * blockDim.x + threadIdx.x;  // 2N: [cntb|cntc] -> [dinvb|dinvc]
  if (i < 2 * NN) dinv[i] = rsqrtf((float)cnt[i] + 1.0f);
}

// ---- parallel 2-level exclusive scan over cnt[2N] -> off[2N], cur[2N] ----
__global__ void k_scan_part(const int* __restrict__ cnt, int* __restrict__ part) {
  int rel = blockIdx.x / SCB, b = blockIdx.x % SCB;
  int n = b * 256 + threadIdx.x;
  int v = (n < NN) ? cnt[rel * NN + n] : 0;
#pragma unroll
  for (int m = 32; m >= 1; m >>= 1) v += __shfl_xor(v, m, 64);
  __shared__ int red[4];
  if ((threadIdx.x & 63) == 0) red[threadIdx.x >> 6] = v;
  __syncthreads();
  if (threadIdx.x == 0) part[rel * SCB + b] = red[0] + red[1] + red[2] + red[3];
}

__global__ void k_scan_base(int* __restrict__ part) {
  __shared__ int s[256];
  int t = threadIdx.x;
  for (int rel = 0; rel < 2; ++rel) {
    int v = (t < SCB) ? part[rel * SCB + t] : 0;
    s[t] = v;
    __syncthreads();
    for (int ofs = 1; ofs < 256; ofs <<= 1) {
      int x = (t >= ofs) ? s[t - ofs] : 0;
      __syncthreads();
      s[t] += x;
      __syncthreads();
    }
    if (t < SCB) part[rel * SCB + t] = s[t] - v;  // exclusive
    __syncthreads();
  }
}

__global__ void k_scan_off(const int* __restrict__ cnt, const int* __restrict__ part,
                           int* __restrict__ off, int* __restrict__ cur) {
  int rel = blockIdx.x / SCB, b = blockIdx.x % SCB;
  int t = threadIdx.x;
  int n = b * 256 + t;
  int v = (n < NN) ? cnt[rel * NN + n] : 0;
  __shared__ int s[256];
  s[t] = v;
  __syncthreads();
  for (int ofs = 1; ofs < 256; ofs <<= 1) {
    int x = (t >= ofs) ? s[t - ofs] : 0;
    __syncthreads();
    s[t] += x;
    __syncthreads();
  }
  if (n < NN) {
    int o = part[rel * SCB + b] + s[t] - v;
    off[rel * NN + n] = o;
    cur[rel * NN + n] = o;
  }
}

__global__ void k_fill(const int* __restrict__ bei, const int* __restrict__ cei,
                       int* __restrict__ curb, int* __restrict__ listb,
                       int* __restrict__ curc, int* __restrict__ listc) {
  int i = blockIdx.x * blockDim.x + threadIdx.x;
  if (i < EE) {
    int dst = bei[EE + i];
    int p = atomicAdd(&curb[dst], 1);
    listb[p] = bei[i];
  } else if (i < 2 * EE) {
    int e = i - EE;
    int dst = cei[EE + e];
    int p = atomicAdd(&curc[dst], 1);
    listc[p] = cei[e];
  }
}

// ---------------- encoder: relu(x@W_enc+b) -> bf16, accumulate BN stats ----------------
__global__ void k_encoder_bf(const float* __restrict__ x, const float* __restrict__ W,
                             const float* __restrict__ b, ushort* __restrict__ hb,
                             float* __restrict__ sum, float* __restrict__ sumsq) {
  int t = threadIdx.x;
  int c = t & 127, r = t >> 7;
  int n0 = blockIdx.x * 64;
  float w0 = W[c], w1 = W[HH + c], w2 = W[2 * HH + c], bb = b[c];
  float ls = 0.f, lss = 0.f;
  for (int rr = r; rr < 64; rr += 2) {
    int n = n0 + rr;
    if (n < NN) {
      float v = fmaxf(x[n * 3] * w0 + x[n * 3 + 1] * w1 + x[n * 3 + 2] * w2 + bb, 0.f);
      ushort u = f2bf(v);
      hb[(size_t)n * HH + c] = u;
      float vr = bf2f(u);          // stats on the rounded value (self-consistent BN)
      ls += vr; lss += vr * vr;
    }
  }
  __shared__ float red[2][HH];
  red[r][c] = ls; __syncthreads();
  if (r == 0) atomicAdd(&sum[c], red[0][c] + red[1][c]);
  __syncthreads();
  red[r][c] = lss; __syncthreads();
  if (r == 0) atomicAdd(&sumsq[c], red[0][c] + red[1][c]);
}

__global__ void k_bn_finalize(const float* __restrict__ sum, const float* __restrict__ sumsq,
                              const float* __restrict__ g, const float* __restrict__ be,
                              float* __restrict__ scale, float* __restrict__ shift, float invn) {
  int c = threadIdx.x;
  float m = sum[c] * invn;
  float v = fmaxf(sumsq[c] * invn - m * m, 0.f);
  float s = g[c] * rsqrtf(v + EPS_);
  scale[c] = s;
  shift[c] = be[c] - m * s;
}

// merged 2-relation finalize; st layout: [sum0,sq0,sum1,sq1,scale0,shift0,scale1,shift1]
__global__ void k_bn_finalize2(float* __restrict__ st, const float* __restrict__ g0,
                               const float* __restrict__ be0, const float* __restrict__ g1,
                               const float* __restrict__ be1, float invn) {
  int t = threadIdx.x;  // 256
  int rel = t >> 7, c = t & 127;
  const float* sum = st + rel * 2 * HH;
  const float* sq  = sum + HH;
  float* scale = st + 4 * HH + rel * 2 * HH;
  float* shift = scale + HH;
  const float* g = rel ? g1 : g0;
  const float* be = rel ? be1 : be0;
  float m = sum[c] * invn;
  float v = fmaxf(sq[c] * invn - m * m, 0.f);
  float s = g[c] * rsqrtf(v + EPS_);
  scale[c] = s;
  shift[c] = be[c] - m * s;
}

__global__ void k_bn_apply_bf(ushort* __restrict__ hb, const float* __restrict__ scale,
                              const float* __restrict__ shift) {
  int i = blockIdx.x * 256 + threadIdx.x;  // i over N*H/4
  if (i * 4 < NN * HH) {
    int base = i * 4, c0 = base & 127;
    ushort4 u = *(ushort4*)&hb[base];
    u.x = f2bf(bf2f(u.x) * scale[c0] + shift[c0]);
    u.y = f2bf(bf2f(u.y) * scale[c0 + 1] + shift[c0 + 1]);
    u.z = f2bf(bf2f(u.z) * scale[c0 + 2] + shift[c0 + 2]);
    u.w = f2bf(bf2f(u.w) * scale[c0 + 3] + shift[c0 + 3]);
    *(ushort4*)&hb[base] = u;
  }
}

// ---------------- weight transposes to bf16 ----------------
__global__ void k_wt128_all(const float* __restrict__ s0, const float* __restrict__ s1,
                            const float* __restrict__ s2, const float* __restrict__ s3,
                            ushort* __restrict__ d0, ushort* __restrict__ d1,
                            ushort* __restrict__ d2, ushort* __restrict__ d3) {
  int i = blockIdx.x * 256 + threadIdx.x;
  if (i < 4 * 128 * 128) {
    int sel = i >> 14, loc = i & 16383;
    int k = loc >> 7, c = loc & 127;
    const float* s = sel == 0 ? s0 : sel == 1 ? s1 : sel == 2 ? s2 : s3;
    ushort* d = sel == 0 ? d0 : sel == 1 ? d1 : sel == 2 ? d2 : d3;
    d[c * 128 + k] = f2bf(s[loc]);
  }
}

__global__ void k_wt256_all(const float* __restrict__ s0, const float* __restrict__ s1,
                            ushort* __restrict__ d0, ushort* __restrict__ d1) {
  int i = blockIdx.x * 256 + threadIdx.x;
  if (i < 2 * 256 * 128) {
    int sel = i >> 15, loc = i & 32767;
    int k = loc >> 7, c = loc & 127;
    const float* s = sel ? s1 : s0;
    ushort* d = sel ? d1 : d0;
    d[c * 256 + k] = f2bf(s[loc]);
  }
}

// ---------------- bf16 GEMM pair: Y{0,1}[N,128] = X[N,128] @ W{0,1} ----------------
__global__ __launch_bounds__(256) void k_gemm_bf2(const ushort* __restrict__ X,
                                                  const ushort* __restrict__ Wt0,
                                                  ushort* __restrict__ Y0,
                                                  const ushort* __restrict__ Wt1,
                                                  ushort* __restrict__ Y1) {
  const int nb = gridDim.x >> 1;
  const int rel = blockIdx.x >= nb;
  const int blk = rel ? blockIdx.x - nb : blockIdx.x;
  const ushort* Wt = rel ? Wt1 : Wt0;
  ushort* Y = rel ? Y1 : Y0;
  const int t = threadIdx.x;
  const int l = t & 63, wid = t >> 6;
  const int wm = wid >> 1, wn = wid & 1;
  const int lr = l & 15, lg = l >> 4;
  const int n0 = blk * 64;
  f32x4 acc[2][4];
#pragma unroll
  for (int mf = 0; mf < 2; ++mf)
#pragma unroll
    for (int nf = 0; nf < 4; ++nf) acc[mf][nf] = (f32x4){0.f, 0.f, 0.f, 0.f};
  int r0 = n0 + wm * 32 + lr;
  int rA = min(r0, NN - 1), rB = min(r0 + 16, NN - 1);
  const ushort* xa = X + (size_t)rA * HH + lg * 8;
  const ushort* xb = X + (size_t)rB * HH + lg * 8;
#pragma unroll
  for (int ks = 0; ks < 4; ++ks) {
    bf16x8 a0 = *(const bf16x8*)(xa + ks * 32);
    bf16x8 a1 = *(const bf16x8*)(xb + ks * 32);
#pragma unroll
    for (int nf = 0; nf < 4; ++nf) {
      int col = wn * 64 + nf * 16 + lr;
      bf16x8 b = *(const bf16x8*)(Wt + col * 128 + ks * 32 + lg * 8);
      acc[0][nf] = __builtin_amdgcn_mfma_f32_16x16x32_bf16(a0, b, acc[0][nf], 0, 0, 0);
      acc[1][nf] = __builtin_amdgcn_mfma_f32_16x16x32_bf16(a1, b, acc[1][nf], 0, 0, 0);
    }
  }
#pragma unroll
  for (int mf = 0; mf < 2; ++mf)
#pragma unroll
    for (int nf = 0; nf < 4; ++nf) {
      int col = wn * 64 + nf * 16 + lr;
#pragma unroll
      for (int j = 0; j < 4; ++j) {
        int row = n0 + wm * 32 + mf * 16 + lg * 4 + j;
        if (row < NN) Y[(size_t)row * HH + col] = f2bf(acc[mf][nf][j]);
      }
    }
}

// ---------------- fused aggregation: bias+self+both relations (+relu) -> bf16 ----------------
template <int RELU>
__global__ void k_agg(const ushort* __restrict__ xwb, const ushort* __restrict__ xwc,
                      const float* __restrict__ dinvb, const float* __restrict__ dinvc,
                      const int* __restrict__ offb, const int* __restrict__ cntb,
                      const int* __restrict__ listb,
                      const int* __restrict__ offc, const int* __restrict__ cntc,
                      const int* __restrict__ listc,
                      const float* __restrict__ bb, const float* __restrict__ bc,
                      ushort* __restrict__ out) {
  int t = threadIdx.x;
  int n = blockIdx.x * 2 + (t >> 7);
  int c = t & 127;
  if (n >= NN) return;
  float dnb = dinvb[n], dnc = dinvc[n];
  float acc = bb[c] + bc[c] + dnb * dnb * bf2f(xwb[(size_t)n * HH + c])
                            + dnc * dnc * bf2f(xwc[(size_t)n * HH + c]);
  int o = offb[n], e = o + cntb[n];
  float s = 0.f;
  for (; o < e; ++o) { int src = listb[o]; s += dinvb[src] * bf2f(xwb[(size_t)src * HH + c]); }
  acc += dnb * s;
  o = offc[n]; e = o + cntc[n];
  s = 0.f;
  for (; o < e; ++o) { int src = listc[o]; s += dinvc[src] * bf2f(xwc[(size_t)src * HH + c]); }
  acc += dnc * s;
  if (RELU) acc = fmaxf(acc, 0.f);
  out[(size_t)n * HH + c] = f2bf(acc);
}

// ---------------- edge MLP v5: B (W1^T) staged in LDS (swizzled), A direct-gather ----------------
// Block = 128 edges, 4 waves; each wave owns 32 edges x all 128 cols, K=256.
// W1^T staged 32KB per half (src-k then dst-k) with byte ^= (col&7)<<4 swizzle so
// ds_read_b128 B-fragments are bank-conflict-free; A rows gathered direct from global.
// PASS2=0: BN stats into st[rel].  PASS2=1: recompute, BN-apply, out = t_hat@W2 + b2.
template <int PASS2>
__global__ __launch_bounds__(256, 4) void k_edge_mlp5(
    const ushort* __restrict__ h2b,
    const int* __restrict__ ei0, const ushort* __restrict__ Wt0, const float* __restrict__ b1_0,
    const int* __restrict__ ei1, const ushort* __restrict__ Wt1, const float* __restrict__ b1_1,
    float* __restrict__ st,
    const float* __restrict__ W2_0, const float* __restrict__ b2_0,
    const float* __restrict__ W2_1, const float* __restrict__ b2_1,
    float* __restrict__ out) {
  const int nb = gridDim.x >> 1;
  const int rel = blockIdx.x >= nb;
  const int blk = rel ? blockIdx.x - nb : blockIdx.x;
  const int* ei = rel ? ei1 : ei0;
  const ushort* W1t = rel ? Wt1 : Wt0;
  const float* b1 = rel ? b1_1 : b1_0;

  __shared__ ushort Bs[128 * 128];      // 32KB: one K-half of W1^T, swizzled
  __shared__ float redA[HH], redB[HH];

  const int t = threadIdx.x;
  const int l = t & 63, wid = t >> 6;
  const int lr = l & 15, lg = l >> 4;
  const int e0 = blk * 128 + wid * 32;  // this wave's 32 edges

  // edge indices + src-row A prefetch issued first (overlap with staging)
  int r0 = min(e0 + lr, EE - 1);
  int r1 = min(e0 + 16 + lr, EE - 1);
  int s0 = ei[r0], d0 = ei[EE + r0];
  int s1 = ei[r1], d1 = ei[EE + r1];

  bf16x8 a0[4], a1[4];
#pragma unroll
  for (int ks = 0; ks < 4; ++ks) {
    a0[ks] = *(const bf16x8*)(h2b + (size_t)s0 * HH + ks * 32 + lg * 8);
    a1[ks] = *(const bf16x8*)(h2b + (size_t)s1 * HH + ks * 32 + lg * 8);
  }

  if (!PASS2) {
    if (t < HH) { redA[t] = 0.f; redB[t] = 0.f; }
  }

  // ---- stage half 0: k 0..127 of every col (2048 x 16B chunks) ----
#pragma unroll
  for (int i = 0; i < 8; ++i) {
    int c = i * 256 + t;
    int col = c >> 4, part = c & 15;
    int lb = (col * 256 + part * 16) ^ ((col & 7) << 4);
    *(bf16x8*)((char*)Bs + lb) = *(const bf16x8*)(W1t + col * 256 + part * 8);
  }
  __syncthreads();

  f32x4 acc[2][8];
#pragma unroll
  for (int mf = 0; mf < 2; ++mf)
#pragma unroll
    for (int nf = 0; nf < 8; ++nf) acc[mf][nf] = (f32x4){0.f, 0.f, 0.f, 0.f};

  // ---- src half compute ----
#pragma unroll
  for (int ks = 0; ks < 4; ++ks) {
#pragma unroll
    for (int nf = 0; nf < 8; ++nf) {
      int col = nf * 16 + lr;
      int lb = (col * 256 + ks * 64 + lg * 16) ^ ((col & 7) << 4);
      bf16x8 b = *(const bf16x8*)((const char*)Bs + lb);
      acc[0][nf] = __builtin_amdgcn_mfma_f32_16x16x32_bf16(a0[ks], b, acc[0][nf], 0, 0, 0);
      acc[1][nf] = __builtin_amdgcn_mfma_f32_16x16x32_bf16(a1[ks], b, acc[1][nf], 0, 0, 0);
    }
  }

  // issue dst-row A loads now (hide under half-1 staging + barriers)
#pragma unroll
  for (int ks = 0; ks < 4; ++ks) {
    a0[ks] = *(const bf16x8*)(h2b + (size_t)d0 * HH + ks * 32 + lg * 8);
    a1[ks] = *(const bf16x8*)(h2b + (size_t)d1 * HH + ks * 32 + lg * 8);
  }
  __syncthreads();   // all waves done reading half-0 Bs

  // ---- stage half 1: k 128..255 ----
#pragma unroll
  for (int i = 0; i < 8; ++i) {
    int c = i * 256 + t;
    int col = c >> 4, part = c & 15;
    int lb = (col * 256 + part * 16) ^ ((col & 7) << 4);
    *(bf16x8*)((char*)Bs + lb) = *(const bf16x8*)(W1t + col * 256 + 128 + part * 8);
  }
  __syncthreads();

  // ---- dst half compute ----
#pragma unroll
  for (int ks = 0; ks < 4; ++ks) {
#pragma unroll
    for (int nf = 0; nf < 8; ++nf) {
      int col = nf * 16 + lr;
      int lb = (col * 256 + ks * 64 + lg * 16) ^ ((col & 7) << 4);
      bf16x8 b = *(const bf16x8*)((const char*)Bs + lb);
      acc[0][nf] = __builtin_amdgcn_mfma_f32_16x16x32_bf16(a0[ks], b, acc[0][nf], 0, 0, 0);
      acc[1][nf] = __builtin_amdgcn_mfma_f32_16x16x32_bf16(a1[ks], b, acc[1][nf], 0, 0, 0);
    }
  }

  if (!PASS2) {
    float* gsum = st + rel * 2 * HH;
    float* gsq  = gsum + HH;
#pragma unroll
    for (int nf = 0; nf < 8; ++nf) {
      int col = nf * 16 + lr;
      float b1c = b1[col];
      float s = 0.f, q = 0.f;
#pragma unroll
      for (int mf = 0; mf < 2; ++mf)
#pragma unroll
        for (int j = 0; j < 4; ++j) {
          int row = e0 + mf * 16 + lg * 4 + j;
          if (row < EE) {
            float v = fmaxf(acc[mf][nf][j] + b1c, 0.f);
            s += v; q += v * v;
          }
        }
      // reduce across the 4 lg-groups (lanes differing in bits 4,5)
      s += __shfl_xor(s, 16, 64); s += __shfl_xor(s, 32, 64);
      q += __shfl_xor(q, 16, 64); q += __shfl_xor(q, 32, 64);
      if (lg == 0) { atomicAdd(&redA[col], s); atomicAdd(&redB[col], q); }
    }
    __syncthreads();
    if (t < HH) {
      atomicAdd(&gsum[t], redA[t]);
      atomicAdd(&gsq[t], redB[t]);
    }
  } else {
    const float* scale = st + 4 * HH + rel * 2 * HH;
    const float* shift = scale + HH;
    const float* W2 = rel ? W2_1 : W2_0;
    const float* b2 = rel ? b2_1 : b2_0;
    float* o = out + (size_t)rel * 2 * EE;
    float p0[2][4], p1[2][4];
#pragma unroll
    for (int mf = 0; mf < 2; ++mf)
#pragma unroll
      for (int j = 0; j < 4; ++j) { p0[mf][j] = 0.f; p1[mf][j] = 0.f; }
#pragma unroll
    for (int nf = 0; nf < 8; ++nf) {
      int col = nf * 16 + lr;
      float b1c = b1[col], sc = scale[col], sh = shift[col];
      float w20 = W2[col * 2], w21 = W2[col * 2 + 1];
#pragma unroll
      for (int mf = 0; mf < 2; ++mf)
#pragma unroll
        for (int j = 0; j < 4; ++j) {
          float v = fmaxf(acc[mf][nf][j] + b1c, 0.f) * sc + sh;
          p0[mf][j] += v * w20;
          p1[mf][j] += v * w21;
        }
    }
    // reduce across the 16 lr lanes (bits 0..3)
#pragma unroll
    for (int m = 8; m >= 1; m >>= 1) {
#pragma unroll
      for (int mf = 0; mf < 2; ++mf)
#pragma unroll
        for (int j = 0; j < 4; ++j) {
          p0[mf][j] += __shfl_xor(p0[mf][j], m, 64);
          p1[mf][j] += __shfl_xor(p1[mf][j], m, 64);
        }
    }
    if (lr == 0) {
      float b20 = b2[0], b21 = b2[1];
#pragma unroll
      for (int mf = 0; mf < 2; ++mf)
#pragma unroll
        for (int j = 0; j < 4; ++j) {
          int row = e0 + mf * 16 + lg * 4 + j;
          if (row < EE) {
            o[(size_t)row * 2 + 0] = p0[mf][j] + b20;
            o[(size_t)row * 2 + 1] = p1[mf][j] + b21;
          }
        }
    }
  }
}

// ---------------- edge types ----------------
__global__ void k_edge_types(float* __restrict__ out) {
  int i = blockIdx.x * 256 + threadIdx.x;
  if (i < 2 * EE) out[(size_t)2 * EE * 2 + i] = (i < EE) ? 0.0f : 1.0f;
}

extern "C" void kernel_launch(void* const* d_in, const int* in_sizes, int n_in,
                              void* d_out, int out_size, void* d_ws, size_t ws_size,
                              hipStream_t stream) {
  const float* x      = (const float*)d_in[0];
  const int*   bei    = (const int*)d_in[1];
  const int*   cei    = (const int*)d_in[2];
  const float* W_enc  = (const float*)d_in[3];
  const float* b_enc  = (const float*)d_in[4];
  const float* g_enc  = (const float*)d_in[5];
  const float* be_enc = (const float*)d_in[6];
  const float* W1b = (const float*)d_in[7];  const float* b1b = (const float*)d_in[8];
  const float* W1c = (const float*)d_in[9];  const float* b1c = (const float*)d_in[10];
  const float* W2b = (const float*)d_in[11]; const float* b2b = (const float*)d_in[12];
  const float* W2c = (const float*)d_in[13]; const float* b2c = (const float*)d_in[14];
  const float* Wbp1 = (const float*)d_in[15]; const float* bbp1 = (const float*)d_in[16];
  const float* gbp  = (const float*)d_in[17]; const float* bebp = (const float*)d_in[18];
  const float* Wbp2 = (const float*)d_in[19]; const float* bbp2 = (const float*)d_in[20];
  const float* Wcp1 = (const float*)d_in[21]; const float* bcp1 = (const float*)d_in[22];
  const float* gcp  = (const float*)d_in[23]; const float* becp = (const float*)d_in[24];
  const float* Wcp2 = (const float*)d_in[25]; const float* bcp2 = (const float*)d_in[26];
  float* out = (float*)d_out;

  // ---- workspace layout (~57 MB) ----
  ushort* hb   = (ushort*)d_ws;                 // h (bf16); later h2  [N*H]
  ushort* h1b  = hb + (size_t)NN * HH;          // h1 bf16
  ushort* xwb  = h1b + (size_t)NN * HH;         // per-relation x@W bf16
  ushort* xwc  = xwb + (size_t)NN * HH;
  ushort* Wt1b = xwc + (size_t)NN * HH;         // 128x128 transposed weights (bf16)
  ushort* Wt1c = Wt1b + 128 * 128;
  ushort* Wt2b = Wt1c + 128 * 128;
  ushort* Wt2c = Wt2b + 128 * 128;
  ushort* Wmb  = Wt2c + 128 * 128;              // MLP W1^T [128][256]
  ushort* Wmc  = Wmb + 256 * 128;
  float* dinv  = (float*)(Wmc + 256 * 128);     // dinvb[N], dinvc[N]
  float* dinvb = dinv, *dinvc = dinv + NN;
  float* st    = dinvc + NN;                    // [sum0,sq0,sum1,sq1,scale0,shift0,scale1,shift1]
  int* cnt  = (int*)(st + 8 * HH);              // cntb[N], cntc[N]
  int* cntb = cnt, *cntc = cnt + NN;
  int* offb = cntc + NN; int* offc = offb + NN;
  int* curb = offc + NN; int* curc = curb + NN;
  int* part = curc + NN;                        // scan partials [2*SCB]
  int* listb = part + 2 * SCB; int* listc = listb + EE;

  // ---- degrees + CSR (parallel scan) ----
  hipMemsetAsync(cnt, 0, sizeof(int) * 2 * NN, stream);
  hipMemsetAsync(st, 0, sizeof(float) * 2 * HH, stream);
  k_count<<<(2 * EE + 255) / 256, 256, 0, stream>>>(bei, cei, cntb, cntc);
  k_dinv<<<(2 * NN + 255) / 256, 256, 0, stream>>>(cnt, dinv);
  k_scan_part<<<2 * SCB, 256, 0, stream>>>(cnt, part);
  k_scan_base<<<1, 256, 0, stream>>>(part);
  k_scan_off<<<2 * SCB, 256, 0, stream>>>(cnt, part, offb, curb);
  k_fill<<<(2 * EE + 255) / 256, 256, 0, stream>>>(bei, cei, curb, listb, curc, listc);

  // ---- encoder + BN -> hb (bf16) ----
  k_encoder_bf<<<(NN + 63) / 64, 256, 0, stream>>>(x, W_enc, b_enc, hb, st, st + HH);
  k_bn_finalize<<<1, 128, 0, stream>>>(st, st + HH, g_enc, be_enc, st + 4 * HH, st + 5 * HH,
                                       1.0f / NN);
  k_bn_apply_bf<<<(NN * HH / 4 + 255) / 256, 256, 0, stream>>>(hb, st + 4 * HH, st + 5 * HH);

  // ---- weight transposes ----
  k_wt128_all<<<(4 * 16384 + 255) / 256, 256, 0, stream>>>(W1b, W1c, W2b, W2c,
                                                           Wt1b, Wt1c, Wt2b, Wt2c);
  k_wt256_all<<<(2 * 32768 + 255) / 256, 256, 0, stream>>>(Wbp1, Wcp1, Wmb, Wmc);

  int gblk = (NN + 63) / 64;
  int ablk = (NN + 1) / 2;
  // ---- GCN layer 1: h1 = relu(agg_b + agg_c) ----
  k_gemm_bf2<<<2 * gblk, 256, 0, stream>>>(hb, Wt1b, xwb, Wt1c, xwc);
  k_agg<1><<<ablk, 256, 0, stream>>>(xwb, xwc, dinvb, dinvc, offb, cntb, listb,
                                     offc, cntc, listc, b1b, b1c, h1b);
  // ---- GCN layer 2: h2 (into hb slot) ----
  k_gemm_bf2<<<2 * gblk, 256, 0, stream>>>(h1b, Wt2b, xwb, Wt2c, xwc);
  k_agg<0><<<ablk, 256, 0, stream>>>(xwb, xwc, dinvb, dinvc, offb, cntb, listb,
                                     offc, cntc, listc, b2b, b2c, hb);

  // ---- edge predictors (both relations per launch) ----
  int mblk = (EE + 127) / 128;
  hipMemsetAsync(st, 0, sizeof(float) * 4 * HH, stream);
  k_edge_mlp5<0><<<2 * mblk, 256, 0, stream>>>(hb, bei, Wmb, bbp1, cei, Wmc, bcp1, st,
                                               nullptr, nullptr, nullptr, nullptr, nullptr);
  k_bn_finalize2<<<1, 256, 0, stream>>>(st, gbp, bebp, gcp, becp, 1.0f / EE);
  k_edge_mlp5<1><<<2 * mblk, 256, 0, stream>>>(hb, bei, Wmb, bbp1, cei, Wmc, bcp1, st,
                                               Wbp2, bbp2, Wcp2, bcp2, out);

  k_edge_types<<<(2 * EE + 255) / 256, 256, 0, stream>>>(out);
}